// Round 5
// baseline (3531.224 us; speedup 1.0000x reference)
//
#include <hip/hip_runtime.h>

#define NN 50000
#define NE 1200000
#define CCH 64
#define NLAYER 8
#define HID 128
#define NG 128
#define BN_EPS 1e-5f
#define SCAN_NB ((NN + 255) / 256)   // 196
#define AGG_CHUNK 2                  // nodes per work-steal grab

// ---- workspace layout (offsets in floats) ----
// [stats(9*128) | pooled(128*64) | counts(128) | wq(64)] <- zeroed by one memsetAsync
enum : size_t {
  OFF_STATS  = 0,
  OFF_POOLED = 1152,
  OFF_COUNTS = 9344,
  OFF_WQ     = 9472,       // 8 ints (one queue counter per layer), padded to 64
  MEMSET_F   = 9536,
  OFF_DEG    = 9536,
  OFF_DIS    = 59536,
  OFF_OFFS   = 109536,     // N+1 (+pad)
  OFF_CURSOR = 159540,
  OFF_PART   = 209540,     // 256 block partials
  OFF_CSRSRC = 209796,
  OFF_H      = 1409796,
  OFF_HW     = 4609796,    // ushort[N*64] (bf16)
  OFF_WP     = 7809796,
  OFF_BIAS2  = 7813892,
  WS_FLOATS  = 7813956
};

__device__ __forceinline__ float bf2f(unsigned int hs) {
  union { unsigned int u; float f; } c; c.u = hs << 16; return c.f;
}
__device__ __forceinline__ unsigned int f2bf(float x) {
  union { float f; unsigned int u; } c; c.f = x;
  return (c.u + 0x7fffu + ((c.u >> 16) & 1u)) >> 16;  // RNE
}

__global__ void init_deg_kernel(float* __restrict__ deg) {
  int i = blockIdx.x * blockDim.x + threadIdx.x;
  if (i < NN) deg[i] = 1.0f;  // self-loop
}

__global__ void count_deg_kernel(const int* __restrict__ ei, float* __restrict__ deg) {
  int e = blockIdx.x * blockDim.x + threadIdx.x;
  if (e < NE) atomicAdd(&deg[ei[NE + e]], 1.0f);
}

// Per-block exclusive scan of (deg-1); also computes dis = rsqrt(deg).
__global__ __launch_bounds__(256) void scan_blocks_kernel(const float* __restrict__ deg,
    int* __restrict__ offs, int* __restrict__ partials, float* __restrict__ dis) {
  int i = blockIdx.x * 256 + threadIdx.x;
  int v = 0;
  if (i < NN) {
    float d = deg[i];
    v = (int)d - 1;
    dis[i] = rsqrtf(d);
  }
  __shared__ int sm[256];
  sm[threadIdx.x] = v;
  __syncthreads();
  for (int d = 1; d < 256; d <<= 1) {
    int add = (threadIdx.x >= d) ? sm[threadIdx.x - d] : 0;
    __syncthreads();
    sm[threadIdx.x] += add;
    __syncthreads();
  }
  if (i < NN) offs[i] = sm[threadIdx.x] - v;  // exclusive within block
  if (threadIdx.x == 255) partials[blockIdx.x] = sm[255];
}

__global__ __launch_bounds__(256) void scan_carry_kernel(int* __restrict__ partials) {
  int t = threadIdx.x;
  int v = (t < SCAN_NB) ? partials[t] : 0;
  __shared__ int sm[256];
  sm[t] = v;
  __syncthreads();
  for (int d = 1; d < 256; d <<= 1) {
    int add = (t >= d) ? sm[t - d] : 0;
    __syncthreads();
    sm[t] += add;
    __syncthreads();
  }
  if (t < SCAN_NB) partials[t] = sm[t] - v;  // exclusive carry per block
}

__global__ __launch_bounds__(256) void scan_apply_kernel(const int* __restrict__ partials,
    int* __restrict__ offs, int* __restrict__ cursor) {
  int i = blockIdx.x * 256 + threadIdx.x;
  if (i < NN) {
    int o = offs[i] + partials[blockIdx.x];
    offs[i] = o;
    cursor[i] = o;
  }
  if (i == 0) offs[NN] = NE;
}

__global__ void csr_fill_kernel(const int* __restrict__ ei,
    int* __restrict__ cursor, int* __restrict__ csr_src) {
  int e = blockIdx.x * blockDim.x + threadIdx.x;
  if (e < NE) {
    int r = ei[e], c = ei[NE + e];
    int p = atomicAdd(&cursor[c], 1);
    csr_src[p] = r;
  }
}

// h = emb[x]; also accumulate BN stats for layer 0
__global__ __launch_bounds__(256) void embed_stats_kernel(const int* __restrict__ x,
    const float* __restrict__ emb, float* __restrict__ h, float* __restrict__ stats0) {
  int c = threadIdx.x & 63;
  int wave = (blockIdx.x * blockDim.x + threadIdx.x) >> 6;
  int nw = (gridDim.x * blockDim.x) >> 6;
  float ls = 0.f, lq = 0.f;
  for (int i = wave; i < NN; i += nw) {
    float v = emb[x[i] * CCH + c];
    h[(size_t)i * CCH + c] = v;
    ls += v; lq += v * v;
  }
  __shared__ float s1[256], s2[256];
  s1[threadIdx.x] = ls; s2[threadIdx.x] = lq;
  __syncthreads();
  if (threadIdx.x < 64) {
    float a = s1[threadIdx.x] + s1[threadIdx.x + 64] + s1[threadIdx.x + 128] + s1[threadIdx.x + 192];
    float b = s2[threadIdx.x] + s2[threadIdx.x + 64] + s2[threadIdx.x + 128] + s2[threadIdx.x + 192];
    atomicAdd(&stats0[c], a);
    atomicAdd(&stats0[64 + c], b);
  }
}

// Fold BN into GEMM: Wp[k][j] = a[k]*W[k][j], bias2[j] = sum_k b2[k]*W[k][j]
__global__ __launch_bounds__(256) void bn_make_kernel(const float* __restrict__ stats,
    const float* __restrict__ gamma, const float* __restrict__ beta,
    const float* __restrict__ W, float* __restrict__ Wp, float* __restrict__ bias2) {
  __shared__ float a[64], b2[64];
  int t = threadIdx.x;
  if (t < 64) {
    float inv_n = 1.0f / (float)NN;
    float m = stats[t] * inv_n;
    float var = stats[64 + t] * inv_n - m * m;
    float rstd = rsqrtf(var + BN_EPS);
    float av = gamma[t] * rstd;
    a[t] = av;
    b2[t] = beta[t] - m * av;
  }
  __syncthreads();
  for (int idx = t; idx < 4096; idx += 256) {
    int k = idx >> 6;
    Wp[idx] = a[k] * W[idx];
  }
  if (t < 64) {
    float s = 0.f;
    for (int k = 0; k < 64; ++k) s += b2[k] * W[k * 64 + t];
    bias2[t] = s;
  }
}

// hw' = bf16((h @ Wp + bias2) * dis[node])  (row-scaled; bf16 halves gather bytes)
__global__ __launch_bounds__(256) void gemm_kernel(const float* __restrict__ h,
    const float* __restrict__ Wp, const float* __restrict__ bias2,
    const float* __restrict__ dis, unsigned short* __restrict__ hwb) {
  __shared__ float Ws[64 * 64];
  __shared__ float HsT[64 * 132];  // [k][node]
  int tid = threadIdx.x;
  int nodeBase = blockIdx.x * 128;
  for (int idx = tid; idx < 4096; idx += 256) Ws[idx] = Wp[idx];
  for (int idx = tid; idx < 8192; idx += 256) {
    int node = idx >> 6, c = idx & 63;
    int gn = nodeBase + node;
    float v = (gn < NN) ? h[(size_t)gn * CCH + c] : 0.f;
    HsT[c * 132 + node] = v;
  }
  __syncthreads();
  int tc = tid & 15;   // channels tc*4..+3
  int tr = tid >> 4;   // nodes tr*8..+7
  float4 bb = *(const float4*)&bias2[tc * 4];
  float acc[8][4];
#pragma unroll
  for (int i = 0; i < 8; ++i) { acc[i][0] = bb.x; acc[i][1] = bb.y; acc[i][2] = bb.z; acc[i][3] = bb.w; }
#pragma unroll 2
  for (int k = 0; k < 64; ++k) {
    float4 wv = *(const float4*)&Ws[k * 64 + tc * 4];
    float4 h0 = *(const float4*)&HsT[k * 132 + tr * 8];
    float4 h1 = *(const float4*)&HsT[k * 132 + tr * 8 + 4];
    float hv[8] = {h0.x, h0.y, h0.z, h0.w, h1.x, h1.y, h1.z, h1.w};
    float wl[4] = {wv.x, wv.y, wv.z, wv.w};
#pragma unroll
    for (int i = 0; i < 8; ++i)
#pragma unroll
      for (int j = 0; j < 4; ++j) acc[i][j] = fmaf(hv[i], wl[j], acc[i][j]);
  }
#pragma unroll
  for (int i = 0; i < 8; ++i) {
    int gn = nodeBase + tr * 8 + i;
    if (gn < NN) {
      float dv = dis[gn];
      uint2 o;
      o.x = f2bf(acc[i][0] * dv) | (f2bf(acc[i][1] * dv) << 16);
      o.y = f2bf(acc[i][2] * dv) | (f2bf(acc[i][3] * dv) << 16);
      *(uint2*)&hwb[(size_t)gn * CCH + tc * 4] = o;
    }
  }
}

// h = relu(h + conv_b + dis_i*(hw'_i + sum_in hw'_src)); fused BN stats.
// Wave-level dynamic work stealing (AGG_CHUNK nodes per grab) + fully
// predicated 16-edge unroll: 8 gathers always in flight per half-wave.
__global__ __launch_bounds__(256) void aggregate_kernel(float* __restrict__ h,
    const unsigned short* __restrict__ hwb, const float* __restrict__ dis,
    const int* __restrict__ offs, const int* __restrict__ csr_src,
    const float* __restrict__ conv_b_l, float* __restrict__ stats_next,
    int* __restrict__ wq) {
  int tid = threadIdx.x;
  int lane = tid & 63;
  int half = lane >> 5;     // which edge of the pair
  int l = lane & 31;        // channel pair: channels 2l, 2l+1
  float2 cb = ((const float2*)conv_b_l)[l];
  float ls0 = 0.f, ls1 = 0.f, lq0 = 0.f, lq1 = 0.f;
  for (;;) {
    int chunk;
    if (lane == 0) chunk = atomicAdd(wq, 1);
    chunk = __shfl(chunk, 0);
    int lo = chunk * AGG_CHUNK;
    if (lo >= NN) break;
    int hi = lo + AGG_CHUNK; if (hi > NN) hi = NN;
    for (int i = lo; i < hi; ++i) {
      float a0, a1;
      if (half == 0) {  // self term (pre-scaled by dis_i)
        unsigned int sv = *(const unsigned int*)&hwb[(size_t)i * CCH + 2 * l];
        a0 = bf2f(sv & 0xffffu); a1 = bf2f(sv >> 16);
      } else { a0 = 0.f; a1 = 0.f; }
      int e0 = offs[i], e1 = offs[i + 1];
      for (int base = e0 + half; base < e1; base += 16) {
        int s[8]; unsigned int v[8]; int ok[8];
#pragma unroll
        for (int u = 0; u < 8; ++u) {
          int idx = base + 2 * u;
          ok[u] = idx < e1;
          int idxc = idx < e1 ? idx : e1 - 1;
          s[u] = csr_src[idxc];
        }
#pragma unroll
        for (int u = 0; u < 8; ++u)
          v[u] = *(const unsigned int*)&hwb[(size_t)s[u] * CCH + 2 * l];
#pragma unroll
        for (int u = 0; u < 8; ++u) {
          unsigned int vv = ok[u] ? v[u] : 0u;
          a0 += bf2f(vv & 0xffffu); a1 += bf2f(vv >> 16);
        }
      }
      a0 += __shfl_xor(a0, 32);
      a1 += __shfl_xor(a1, 32);
      if (half == 0) {
        float2 hv = ((const float2*)h)[(size_t)i * 32 + l];
        float d = dis[i];
        float v0 = hv.x + cb.x + d * a0;
        float v1 = hv.y + cb.y + d * a1;
        v0 = v0 > 0.f ? v0 : 0.f;
        v1 = v1 > 0.f ? v1 : 0.f;
        float2 o; o.x = v0; o.y = v1;
        ((float2*)h)[(size_t)i * 32 + l] = o;
        ls0 += v0; lq0 += v0 * v0; ls1 += v1; lq1 += v1 * v1;
      }
    }
  }
  __shared__ float2 s1[256], s2[256];
  float2 t1; t1.x = ls0; t1.y = ls1;
  float2 t2; t2.x = lq0; t2.y = lq1;
  s1[tid] = t1; s2[tid] = t2;
  __syncthreads();
  if (tid < 64) {  // tid = channel c; lane c>>1 component c&1 of each wave
    int pair = tid >> 1, comp = tid & 1;
    float a = 0.f, b = 0.f;
#pragma unroll
    for (int w = 0; w < 4; ++w) {
      float2 u1 = s1[w * 64 + pair];
      float2 u2 = s2[w * 64 + pair];
      a += comp ? u1.y : u1.x;
      b += comp ? u2.y : u2.x;
    }
    atomicAdd(&stats_next[tid], a);
    atomicAdd(&stats_next[64 + tid], b);
  }
}

// batch is SORTED: chunked per-wave register accumulation, one atomic per
// graph-boundary per channel.
__global__ __launch_bounds__(256) void pool_kernel(const float* __restrict__ h,
    const int* __restrict__ batch, float* __restrict__ pooled, float* __restrict__ counts) {
  int c = threadIdx.x & 63;
  int wid = (blockIdx.x * blockDim.x + threadIdx.x) >> 6;
  int nw = (gridDim.x * blockDim.x) >> 6;
  int chunk = (NN + nw - 1) / nw;
  int lo = wid * chunk;
  int hi = lo + chunk; if (hi > NN) hi = NN;
  if (lo >= hi) return;
  int g = batch[lo];
  float acc = 0.f, cnt = 0.f;
  for (int i = lo; i < hi; ++i) {
    int gi = batch[i];
    if (gi != g) {
      atomicAdd(&pooled[g * CCH + c], acc);
      if (c == 0) atomicAdd(&counts[g], cnt);
      g = gi; acc = 0.f; cnt = 0.f;
    }
    acc += h[(size_t)i * CCH + c];
    cnt += 1.f;
  }
  atomicAdd(&pooled[g * CCH + c], acc);
  if (c == 0) atomicAdd(&counts[g], cnt);
}

__global__ __launch_bounds__(128) void mlp_kernel(const float* __restrict__ pooled,
    const float* __restrict__ counts, const float* __restrict__ hid_w,
    const float* __restrict__ hid_b, const float* __restrict__ out_w,
    const float* __restrict__ out_b, float* __restrict__ out) {
  int g = blockIdx.x;
  int t = threadIdx.x;  // 128 threads
  __shared__ float p[64], hid[128];
  if (t < 64) {
    float cnt = counts[g];
    cnt = cnt > 1.f ? cnt : 1.f;
    p[t] = pooled[g * CCH + t] / cnt;
  }
  __syncthreads();
  float acc = hid_b[t];
  for (int k = 0; k < 64; ++k) acc = fmaf(p[k], hid_w[k * HID + t], acc);
  acc = acc > 0.f ? acc : 0.f;
  hid[t] = acc;
  __syncthreads();
  if (t < 64) {
    float o = out_b[t];
    for (int j = 0; j < 128; ++j) o = fmaf(hid[j], out_w[j * CCH + t], o);
    out[g * CCH + t] = o;
  }
}

extern "C" void kernel_launch(void* const* d_in, const int* in_sizes, int n_in,
                              void* d_out, int out_size, void* d_ws, size_t ws_size,
                              hipStream_t stream) {
  const int* x       = (const int*)d_in[0];
  const int* ei      = (const int*)d_in[1];
  const int* batch   = (const int*)d_in[2];
  const float* emb   = (const float*)d_in[3];
  const float* gamma = (const float*)d_in[4];
  const float* beta  = (const float*)d_in[5];
  const float* convw = (const float*)d_in[6];
  const float* convb = (const float*)d_in[7];
  const float* hid_w = (const float*)d_in[8];
  const float* hid_b = (const float*)d_in[9];
  const float* out_w = (const float*)d_in[10];
  const float* out_b = (const float*)d_in[11];
  float* out = (float*)d_out;

  float* ws     = (float*)d_ws;
  float* stats  = ws + OFF_STATS;
  float* pooled = ws + OFF_POOLED;
  float* counts = ws + OFF_COUNTS;
  int*   wq     = (int*)(ws + OFF_WQ);
  float* deg    = ws + OFF_DEG;
  float* dis    = ws + OFF_DIS;
  int*   offs   = (int*)(ws + OFF_OFFS);
  int*   cursor = (int*)(ws + OFF_CURSOR);
  int*   part   = (int*)(ws + OFF_PART);
  int*   csrsrc = (int*)(ws + OFF_CSRSRC);
  float* h      = ws + OFF_H;
  unsigned short* hwb = (unsigned short*)(ws + OFF_HW);
  float* wp     = ws + OFF_WP;
  float* bias2  = ws + OFF_BIAS2;

  hipMemsetAsync(ws, 0, MEMSET_F * sizeof(float), stream);
  init_deg_kernel<<<(NN + 255) / 256, 256, 0, stream>>>(deg);
  count_deg_kernel<<<(NE + 255) / 256, 256, 0, stream>>>(ei, deg);
  scan_blocks_kernel<<<SCAN_NB, 256, 0, stream>>>(deg, offs, part, dis);
  scan_carry_kernel<<<1, 256, 0, stream>>>(part);
  scan_apply_kernel<<<SCAN_NB, 256, 0, stream>>>(part, offs, cursor);
  csr_fill_kernel<<<(NE + 255) / 256, 256, 0, stream>>>(ei, cursor, csrsrc);
  embed_stats_kernel<<<512, 256, 0, stream>>>(x, emb, h, stats);

  for (int l = 0; l < NLAYER; ++l) {
    bn_make_kernel<<<1, 256, 0, stream>>>(stats + l * 128, gamma + l * 64, beta + l * 64,
                                          convw + l * 4096, wp, bias2);
    gemm_kernel<<<(NN + 127) / 128, 256, 0, stream>>>(h, wp, bias2, dis, hwb);
    aggregate_kernel<<<2048, 256, 0, stream>>>(h, hwb, dis, offs, csrsrc,
                                               convb + l * 64, stats + (l + 1) * 128,
                                               wq + l);
  }

  pool_kernel<<<128, 256, 0, stream>>>(h, batch, pooled, counts);
  mlp_kernel<<<NG, 128, 0, stream>>>(pooled, counts, hid_w, hid_b, out_w, out_b, out);
}

// Round 6
// 998.414 us; speedup vs baseline: 3.5368x; 3.5368x over previous
//
#include <hip/hip_runtime.h>

#define NN 50000
#define NE 1200000
#define CCH 64
#define NLAYER 8
#define HID 128
#define NG 128
#define BN_EPS 1e-5f
#define SCAN_NB ((NN + 255) / 256)   // 196

// ---- workspace layout (offsets in floats) ----
// [stats(9*128) | pooled(128*64) | counts(128) | pad(64)] <- zeroed by one memsetAsync
enum : size_t {
  OFF_STATS  = 0,
  OFF_POOLED = 1152,
  OFF_COUNTS = 9344,
  MEMSET_F   = 9536,
  OFF_DEG    = 9536,
  OFF_DIS    = 59536,
  OFF_OFFS   = 109536,     // N+1 (+pad)
  OFF_CURSOR = 159540,
  OFF_PART   = 209540,     // 256 block partials
  OFF_CSRSRC = 209796,
  OFF_H      = 1409796,
  OFF_HW     = 4609796,    // ushort[N*64] (bf16)
  WS_FLOATS  = 7809796
};

__device__ __forceinline__ float bf2f(unsigned int hs) {
  union { unsigned int u; float f; } c; c.u = hs << 16; return c.f;
}
__device__ __forceinline__ unsigned int f2bf(float x) {
  union { float f; unsigned int u; } c; c.f = x;
  return (c.u + 0x7fffu + ((c.u >> 16) & 1u)) >> 16;  // RNE
}

__global__ void init_deg_kernel(float* __restrict__ deg) {
  int i = blockIdx.x * blockDim.x + threadIdx.x;
  if (i < NN) deg[i] = 1.0f;  // self-loop
}

__global__ void count_deg_kernel(const int* __restrict__ ei, float* __restrict__ deg) {
  int e = blockIdx.x * blockDim.x + threadIdx.x;
  if (e < NE) atomicAdd(&deg[ei[NE + e]], 1.0f);
}

// Per-block exclusive scan of (deg-1); also computes dis = rsqrt(deg).
__global__ __launch_bounds__(256) void scan_blocks_kernel(const float* __restrict__ deg,
    int* __restrict__ offs, int* __restrict__ partials, float* __restrict__ dis) {
  int i = blockIdx.x * 256 + threadIdx.x;
  int v = 0;
  if (i < NN) {
    float d = deg[i];
    v = (int)d - 1;
    dis[i] = rsqrtf(d);
  }
  __shared__ int sm[256];
  sm[threadIdx.x] = v;
  __syncthreads();
  for (int d = 1; d < 256; d <<= 1) {
    int add = (threadIdx.x >= d) ? sm[threadIdx.x - d] : 0;
    __syncthreads();
    sm[threadIdx.x] += add;
    __syncthreads();
  }
  if (i < NN) offs[i] = sm[threadIdx.x] - v;  // exclusive within block
  if (threadIdx.x == 255) partials[blockIdx.x] = sm[255];
}

__global__ __launch_bounds__(256) void scan_carry_kernel(int* __restrict__ partials) {
  int t = threadIdx.x;
  int v = (t < SCAN_NB) ? partials[t] : 0;
  __shared__ int sm[256];
  sm[t] = v;
  __syncthreads();
  for (int d = 1; d < 256; d <<= 1) {
    int add = (t >= d) ? sm[t - d] : 0;
    __syncthreads();
    sm[t] += add;
    __syncthreads();
  }
  if (t < SCAN_NB) partials[t] = sm[t] - v;  // exclusive carry per block
}

__global__ __launch_bounds__(256) void scan_apply_kernel(const int* __restrict__ partials,
    int* __restrict__ offs, int* __restrict__ cursor) {
  int i = blockIdx.x * 256 + threadIdx.x;
  if (i < NN) {
    int o = offs[i] + partials[blockIdx.x];
    offs[i] = o;
    cursor[i] = o;
  }
  if (i == 0) offs[NN] = NE;
}

__global__ void csr_fill_kernel(const int* __restrict__ ei,
    int* __restrict__ cursor, int* __restrict__ csr_src) {
  int e = blockIdx.x * blockDim.x + threadIdx.x;
  if (e < NE) {
    int r = ei[e], c = ei[NE + e];
    int p = atomicAdd(&cursor[c], 1);
    csr_src[p] = r;
  }
}

// h = emb[x]; also accumulate BN stats for layer 0
__global__ __launch_bounds__(256) void embed_stats_kernel(const int* __restrict__ x,
    const float* __restrict__ emb, float* __restrict__ h, float* __restrict__ stats0) {
  int c = threadIdx.x & 63;
  int wave = (blockIdx.x * blockDim.x + threadIdx.x) >> 6;
  int nw = (gridDim.x * blockDim.x) >> 6;
  float ls = 0.f, lq = 0.f;
  for (int i = wave; i < NN; i += nw) {
    float v = emb[x[i] * CCH + c];
    h[(size_t)i * CCH + c] = v;
    ls += v; lq += v * v;
  }
  __shared__ float s1[256], s2[256];
  s1[threadIdx.x] = ls; s2[threadIdx.x] = lq;
  __syncthreads();
  if (threadIdx.x < 64) {
    float a = s1[threadIdx.x] + s1[threadIdx.x + 64] + s1[threadIdx.x + 128] + s1[threadIdx.x + 192];
    float b = s2[threadIdx.x] + s2[threadIdx.x + 64] + s2[threadIdx.x + 128] + s2[threadIdx.x + 192];
    atomicAdd(&stats0[c], a);
    atomicAdd(&stats0[64 + c], b);
  }
}

// Fused BN-fold + GEMM: hw' = bf16(((h - m)*rstd*gamma + beta) @ W * dis[node])
// Each block recomputes the BN fold (a[k], b2[k], bias2[j]) redundantly (cheap,
// W is L2-resident). HsT stride 133: (5c+node)%32 -> conflict-free staging writes.
__global__ __launch_bounds__(256) void gemm_kernel(const float* __restrict__ h,
    const float* __restrict__ W, const float* __restrict__ gamma,
    const float* __restrict__ beta, const float* __restrict__ stats,
    const float* __restrict__ dis, unsigned short* __restrict__ hwb) {
  __shared__ float Ws[64 * 64];
  __shared__ float HsT[64 * 133];
  __shared__ float sm_a[64], sm_b2[64], sm_bias2[64];
  int tid = threadIdx.x;
  if (tid < 64) {
    float inv_n = 1.0f / (float)NN;
    float m = stats[tid] * inv_n;
    float var = stats[64 + tid] * inv_n - m * m;
    float rstd = rsqrtf(var + BN_EPS);
    float av = gamma[tid] * rstd;
    sm_a[tid] = av;
    sm_b2[tid] = beta[tid] - m * av;
  }
  __syncthreads();
  int nodeBase = blockIdx.x * 128;
  for (int idx = tid; idx < 4096; idx += 256) Ws[idx] = sm_a[idx >> 6] * W[idx];
  for (int idx = tid; idx < 8192; idx += 256) {
    int node = idx >> 6, c = idx & 63;
    int gn = nodeBase + node;
    float v = (gn < NN) ? h[(size_t)gn * CCH + c] : 0.f;
    HsT[c * 133 + node] = v;
  }
  if (tid < 64) {
    float s = 0.f;
    for (int k = 0; k < 64; ++k) s += sm_b2[k] * W[k * 64 + tid];
    sm_bias2[tid] = s;
  }
  __syncthreads();
  int tc = tid & 15;   // channels tc*4..+3
  int tr = tid >> 4;   // nodes tr*8..+7
  float4 bb = *(const float4*)&sm_bias2[tc * 4];
  float acc[8][4];
#pragma unroll
  for (int i = 0; i < 8; ++i) { acc[i][0] = bb.x; acc[i][1] = bb.y; acc[i][2] = bb.z; acc[i][3] = bb.w; }
#pragma unroll 2
  for (int k = 0; k < 64; ++k) {
    float4 wv = *(const float4*)&Ws[k * 64 + tc * 4];
    float4 h0 = *(const float4*)&HsT[k * 133 + tr * 8];
    float4 h1 = *(const float4*)&HsT[k * 133 + tr * 8 + 4];
    float hv[8] = {h0.x, h0.y, h0.z, h0.w, h1.x, h1.y, h1.z, h1.w};
    float wl[4] = {wv.x, wv.y, wv.z, wv.w};
#pragma unroll
    for (int i = 0; i < 8; ++i)
#pragma unroll
      for (int j = 0; j < 4; ++j) acc[i][j] = fmaf(hv[i], wl[j], acc[i][j]);
  }
#pragma unroll
  for (int i = 0; i < 8; ++i) {
    int gn = nodeBase + tr * 8 + i;
    if (gn < NN) {
      float dv = dis[gn];
      uint2 o;
      o.x = f2bf(acc[i][0] * dv) | (f2bf(acc[i][1] * dv) << 16);
      o.y = f2bf(acc[i][2] * dv) | (f2bf(acc[i][3] * dv) << 16);
      *(uint2*)&hwb[(size_t)gn * CCH + tc * 4] = o;
    }
  }
}

// h = relu(h + conv_b + dis_i*(hw'_i + sum_in hw'_src)); fused BN stats.
// CHANNEL-SPLIT + XCD AFFINITY: half = (blockIdx&7)>>2 so XCDs 0-3 only touch
// channels 0-31 (3.2MB, fits a 4MiB per-XCD L2) and XCDs 4-7 channels 32-63.
// Quarter-wave (16 lanes) per edge: one 64B line per gather, 8 edges in
// flight per wave. Static node chunks (round-5's global ticket counter
// serialized the device - reverted).
__global__ __launch_bounds__(256) void aggregate_kernel(float* __restrict__ h,
    const unsigned short* __restrict__ hwb, const float* __restrict__ dis,
    const int* __restrict__ offs, const int* __restrict__ csr_src,
    const float* __restrict__ conv_b_l, float* __restrict__ stats_next) {
  int tid = threadIdx.x;
  int b = blockIdx.x;
  int half = (b >> 2) & 1;               // xcd = b&7 ; half = xcd>>2
  int subIdx = (b >> 3) * 4 + (b & 3);   // 0..(gridDim/2 - 1) within half
  int wid = subIdx * 4 + (tid >> 6);
  int nwHalf = (gridDim.x >> 1) * 4;
  int chunk = (NN + nwHalf - 1) / nwHalf;
  int lo = wid * chunk;
  int hi = lo + chunk; if (hi > NN) hi = NN;
  int lane = tid & 63;
  int slot = lane >> 4;                  // which edge of the quad
  int l = lane & 15;                     // channel pair within half
  int cbase = half * 32;                 // first channel of this half
  float2 cb = ((const float2*)conv_b_l)[half * 16 + l];
  float ls0 = 0.f, ls1 = 0.f, lq0 = 0.f, lq1 = 0.f;
  for (int i = lo; i < hi; ++i) {
    float a0 = 0.f, a1 = 0.f;
    if (slot == 0) {  // self term (pre-scaled by dis_i)
      unsigned int sv = *(const unsigned int*)&hwb[(size_t)i * CCH + cbase + 2 * l];
      a0 = bf2f(sv & 0xffffu); a1 = bf2f(sv >> 16);
    }
    int e0 = offs[i], e1 = offs[i + 1];
    for (int base = e0; base < e1; base += 8) {
      int iA = base + slot, iB = base + 4 + slot;
      int okA = iA < e1, okB = iB < e1;
      int sA = csr_src[okA ? iA : e1 - 1];
      int sB = csr_src[okB ? iB : e1 - 1];
      unsigned int uA = *(const unsigned int*)&hwb[(size_t)sA * CCH + cbase + 2 * l];
      unsigned int uB = *(const unsigned int*)&hwb[(size_t)sB * CCH + cbase + 2 * l];
      uA = okA ? uA : 0u;
      uB = okB ? uB : 0u;
      a0 += bf2f(uA & 0xffffu) + bf2f(uB & 0xffffu);
      a1 += bf2f(uA >> 16) + bf2f(uB >> 16);
    }
    a0 += __shfl_xor(a0, 16); a0 += __shfl_xor(a0, 32);
    a1 += __shfl_xor(a1, 16); a1 += __shfl_xor(a1, 32);
    if (slot == 0) {
      float2 hv = ((const float2*)h)[(size_t)i * 32 + half * 16 + l];
      float d = dis[i];
      float v0 = hv.x + cb.x + d * a0;
      float v1 = hv.y + cb.y + d * a1;
      v0 = v0 > 0.f ? v0 : 0.f;
      v1 = v1 > 0.f ? v1 : 0.f;
      float2 o; o.x = v0; o.y = v1;
      ((float2*)h)[(size_t)i * 32 + half * 16 + l] = o;
      ls0 += v0; lq0 += v0 * v0; ls1 += v1; lq1 += v1 * v1;
    }
  }
  __shared__ float2 s1[256], s2[256];
  float2 t1; t1.x = ls0; t1.y = ls1;
  float2 t2; t2.x = lq0; t2.y = lq1;
  s1[tid] = t1; s2[tid] = t2;
  __syncthreads();
  if (tid < 32) {  // this block covers 32 channels: cbase + tid
    int pair = tid >> 1, comp = tid & 1;  // lane (pair) of slot0 in each wave
    float a = 0.f, bb = 0.f;
#pragma unroll
    for (int w = 0; w < 4; ++w) {
      float2 u1 = s1[w * 64 + pair];
      float2 u2 = s2[w * 64 + pair];
      a += comp ? u1.y : u1.x;
      bb += comp ? u2.y : u2.x;
    }
    atomicAdd(&stats_next[cbase + tid], a);
    atomicAdd(&stats_next[64 + cbase + tid], bb);
  }
}

// batch is SORTED: chunked per-wave register accumulation, one atomic per
// graph-boundary per channel.
__global__ __launch_bounds__(256) void pool_kernel(const float* __restrict__ h,
    const int* __restrict__ batch, float* __restrict__ pooled, float* __restrict__ counts) {
  int c = threadIdx.x & 63;
  int wid = (blockIdx.x * blockDim.x + threadIdx.x) >> 6;
  int nw = (gridDim.x * blockDim.x) >> 6;
  int chunk = (NN + nw - 1) / nw;
  int lo = wid * chunk;
  int hi = lo + chunk; if (hi > NN) hi = NN;
  if (lo >= hi) return;
  int g = batch[lo];
  float acc = 0.f, cnt = 0.f;
  for (int i = lo; i < hi; ++i) {
    int gi = batch[i];
    if (gi != g) {
      atomicAdd(&pooled[g * CCH + c], acc);
      if (c == 0) atomicAdd(&counts[g], cnt);
      g = gi; acc = 0.f; cnt = 0.f;
    }
    acc += h[(size_t)i * CCH + c];
    cnt += 1.f;
  }
  atomicAdd(&pooled[g * CCH + c], acc);
  if (c == 0) atomicAdd(&counts[g], cnt);
}

__global__ __launch_bounds__(128) void mlp_kernel(const float* __restrict__ pooled,
    const float* __restrict__ counts, const float* __restrict__ hid_w,
    const float* __restrict__ hid_b, const float* __restrict__ out_w,
    const float* __restrict__ out_b, float* __restrict__ out) {
  int g = blockIdx.x;
  int t = threadIdx.x;  // 128 threads
  __shared__ float p[64], hid[128];
  if (t < 64) {
    float cnt = counts[g];
    cnt = cnt > 1.f ? cnt : 1.f;
    p[t] = pooled[g * CCH + t] / cnt;
  }
  __syncthreads();
  float acc = hid_b[t];
  for (int k = 0; k < 64; ++k) acc = fmaf(p[k], hid_w[k * HID + t], acc);
  acc = acc > 0.f ? acc : 0.f;
  hid[t] = acc;
  __syncthreads();
  if (t < 64) {
    float o = out_b[t];
    for (int j = 0; j < 128; ++j) o = fmaf(hid[j], out_w[j * CCH + t], o);
    out[g * CCH + t] = o;
  }
}

extern "C" void kernel_launch(void* const* d_in, const int* in_sizes, int n_in,
                              void* d_out, int out_size, void* d_ws, size_t ws_size,
                              hipStream_t stream) {
  const int* x       = (const int*)d_in[0];
  const int* ei      = (const int*)d_in[1];
  const int* batch   = (const int*)d_in[2];
  const float* emb   = (const float*)d_in[3];
  const float* gamma = (const float*)d_in[4];
  const float* beta  = (const float*)d_in[5];
  const float* convw = (const float*)d_in[6];
  const float* convb = (const float*)d_in[7];
  const float* hid_w = (const float*)d_in[8];
  const float* hid_b = (const float*)d_in[9];
  const float* out_w = (const float*)d_in[10];
  const float* out_b = (const float*)d_in[11];
  float* out = (float*)d_out;

  float* ws     = (float*)d_ws;
  float* stats  = ws + OFF_STATS;
  float* pooled = ws + OFF_POOLED;
  float* counts = ws + OFF_COUNTS;
  float* deg    = ws + OFF_DEG;
  float* dis    = ws + OFF_DIS;
  int*   offs   = (int*)(ws + OFF_OFFS);
  int*   cursor = (int*)(ws + OFF_CURSOR);
  int*   part   = (int*)(ws + OFF_PART);
  int*   csrsrc = (int*)(ws + OFF_CSRSRC);
  float* h      = ws + OFF_H;
  unsigned short* hwb = (unsigned short*)(ws + OFF_HW);

  hipMemsetAsync(ws, 0, MEMSET_F * sizeof(float), stream);
  init_deg_kernel<<<(NN + 255) / 256, 256, 0, stream>>>(deg);
  count_deg_kernel<<<(NE + 255) / 256, 256, 0, stream>>>(ei, deg);
  scan_blocks_kernel<<<SCAN_NB, 256, 0, stream>>>(deg, offs, part, dis);
  scan_carry_kernel<<<1, 256, 0, stream>>>(part);
  scan_apply_kernel<<<SCAN_NB, 256, 0, stream>>>(part, offs, cursor);
  csr_fill_kernel<<<(NE + 255) / 256, 256, 0, stream>>>(ei, cursor, csrsrc);
  embed_stats_kernel<<<512, 256, 0, stream>>>(x, emb, h, stats);

  for (int l = 0; l < NLAYER; ++l) {
    gemm_kernel<<<(NN + 127) / 128, 256, 0, stream>>>(h, convw + l * 4096,
                                                      gamma + l * 64, beta + l * 64,
                                                      stats + l * 128, dis, hwb);
    aggregate_kernel<<<2048, 256, 0, stream>>>(h, hwb, dis, offs, csrsrc,
                                               convb + l * 64, stats + (l + 1) * 128);
  }

  pool_kernel<<<128, 256, 0, stream>>>(h, batch, pooled, counts);
  mlp_kernel<<<NG, 128, 0, stream>>>(pooled, counts, hid_w, hid_b, out_w, out_b, out);
}

// Round 7
// 937.250 us; speedup vs baseline: 3.7676x; 1.0653x over previous
//
#include <hip/hip_runtime.h>

#define NN 50000
#define NE 1200000
#define CCH 64
#define NLAYER 8
#define HID 128
#define NG 128
#define BN_EPS 1e-5f
#define SCAN_NB ((NN + 255) / 256)   // 196 blocks / buckets
#define EDGE_CHUNK 8192              // edges per bucket_scatter block

// ---- workspace layout (offsets in floats) ----
// [stats(9*128) | pooled(128*64) | counts(128) | gcur(256)] <- zeroed by one memsetAsync
enum : size_t {
  OFF_STATS  = 0,
  OFF_POOLED = 1152,
  OFF_COUNTS = 9344,
  OFF_GCUR   = 9472,       // 196 bucket cursors (ints)
  MEMSET_F   = 9728,
  OFF_DEG    = 9728,       // int[N]
  OFF_DIS    = 59728,
  OFF_OFFS   = 109728,     // N+1 (+pad)
  OFF_PART   = 159732,     // 256 block partials
  OFF_CSRSRC = 159988,     // int[E]
  OFF_H      = 1359988,    // float[N*64]
  OFF_HW     = 4559988,    // ushort[N*64] (bf16); phase-A staging (uint[E]) aliases this
  WS_FLOATS  = 6159988
};

__device__ __forceinline__ float bf2f(unsigned int hs) {
  union { unsigned int u; float f; } c; c.u = hs << 16; return c.f;
}
__device__ __forceinline__ unsigned int f2bf(float x) {
  union { float f; unsigned int u; } c; c.f = x;
  return (c.u + 0x7fffu + ((c.u >> 16) & 1u)) >> 16;  // RNE
}

__global__ void init_deg_kernel(int* __restrict__ deg) {
  int i = blockIdx.x * blockDim.x + threadIdx.x;
  if (i < NN) deg[i] = 1;  // self-loop
}

__global__ void count_deg_kernel(const int* __restrict__ ei, int* __restrict__ deg) {
  int e = blockIdx.x * blockDim.x + threadIdx.x;
  if (e < NE) atomicAdd(&deg[ei[NE + e]], 1);
}

// Per-block exclusive scan of (deg-1); also computes dis = rsqrt(deg).
__global__ __launch_bounds__(256) void scan_blocks_kernel(const int* __restrict__ deg,
    int* __restrict__ offs, int* __restrict__ partials, float* __restrict__ dis) {
  int i = blockIdx.x * 256 + threadIdx.x;
  int v = 0;
  if (i < NN) {
    int d = deg[i];
    v = d - 1;
    dis[i] = rsqrtf((float)d);
  }
  __shared__ int sm[256];
  sm[threadIdx.x] = v;
  __syncthreads();
  for (int d = 1; d < 256; d <<= 1) {
    int add = (threadIdx.x >= d) ? sm[threadIdx.x - d] : 0;
    __syncthreads();
    sm[threadIdx.x] += add;
    __syncthreads();
  }
  if (i < NN) offs[i] = sm[threadIdx.x] - v;  // exclusive within block
  if (threadIdx.x == 255) partials[blockIdx.x] = sm[255];
}

__global__ __launch_bounds__(256) void scan_carry_kernel(int* __restrict__ partials) {
  int t = threadIdx.x;
  int v = (t < SCAN_NB) ? partials[t] : 0;
  __shared__ int sm[256];
  sm[t] = v;
  __syncthreads();
  for (int d = 1; d < 256; d <<= 1) {
    int add = (t >= d) ? sm[t - d] : 0;
    __syncthreads();
    sm[t] += add;
    __syncthreads();
  }
  if (t < SCAN_NB) partials[t] = sm[t] - v;  // exclusive carry per block
}

__global__ __launch_bounds__(256) void scan_apply_kernel(const int* __restrict__ partials,
    int* __restrict__ offs) {
  int i = blockIdx.x * 256 + threadIdx.x;
  if (i < NN) offs[i] += partials[blockIdx.x];
  if (i == 0) offs[NN] = NE;
}

// ---- CSR build phase A: bucket edges by dst>>8 into staging (packed u32).
// Bucket b's staging region IS its final CSR region [offs[256b], offs[256(b+1)]).
// Per-block LDS histogram + one global atomic per (block,bucket) range-grab:
// writes are block-private ~40-entry runs -> near-full cache-line utilization.
__global__ __launch_bounds__(256) void bucket_scatter_kernel(const int* __restrict__ ei,
    const int* __restrict__ offs, int* __restrict__ gcur, unsigned int* __restrict__ staging) {
  __shared__ int bcnt[SCAN_NB];
  __shared__ int bbase[SCAN_NB];
  int tid = threadIdx.x;
  int lo = blockIdx.x * EDGE_CHUNK;
  int hi = lo + EDGE_CHUNK; if (hi > NE) hi = NE;
  for (int b = tid; b < SCAN_NB; b += 256) bcnt[b] = 0;
  __syncthreads();
  for (int e = lo + tid; e < hi; e += 256)
    atomicAdd(&bcnt[ei[NE + e] >> 8], 1);
  __syncthreads();
  for (int b = tid; b < SCAN_NB; b += 256) {
    int c = bcnt[b];
    bbase[b] = c ? (offs[b << 8] + atomicAdd(&gcur[b], c)) : 0;
    bcnt[b] = 0;
  }
  __syncthreads();
  for (int e = lo + tid; e < hi; e += 256) {
    int src = ei[e], dst = ei[NE + e];
    int b = dst >> 8;
    int p = bbase[b] + atomicAdd(&bcnt[b], 1);
    staging[p] = ((unsigned int)(dst & 255) << 16) | (unsigned int)src;
  }
}

// ---- CSR build phase B: one block per bucket; LDS cursors seeded from offs;
// unpack staging and place src at final position. All per-edge atomics are LDS;
// final writes land in this block's private ~26KB window (L2-resident).
__global__ __launch_bounds__(256) void bucket_fill_kernel(const unsigned int* __restrict__ staging,
    const int* __restrict__ offs, int* __restrict__ csr_src) {
  __shared__ int ncur[256];
  int b = blockIdx.x;
  int nodeBase = b << 8;
  int tid = threadIdx.x;
  int nHi = nodeBase + 256; if (nHi > NN) nHi = NN;
  int nLoc = nHi - nodeBase;
  if (tid < nLoc) ncur[tid] = offs[nodeBase + tid];
  __syncthreads();
  int r0 = offs[nodeBase], r1 = offs[nHi];
  for (int e = r0 + tid; e < r1; e += 256) {
    unsigned int v = staging[e];
    int p = atomicAdd(&ncur[v >> 16], 1);
    csr_src[p] = (int)(v & 0xffffu);
  }
}

// h = emb[x]; also accumulate BN stats for layer 0
__global__ __launch_bounds__(256) void embed_stats_kernel(const int* __restrict__ x,
    const float* __restrict__ emb, float* __restrict__ h, float* __restrict__ stats0) {
  int c = threadIdx.x & 63;
  int wave = (blockIdx.x * blockDim.x + threadIdx.x) >> 6;
  int nw = (gridDim.x * blockDim.x) >> 6;
  float ls = 0.f, lq = 0.f;
  for (int i = wave; i < NN; i += nw) {
    float v = emb[x[i] * CCH + c];
    h[(size_t)i * CCH + c] = v;
    ls += v; lq += v * v;
  }
  __shared__ float s1[256], s2[256];
  s1[threadIdx.x] = ls; s2[threadIdx.x] = lq;
  __syncthreads();
  if (threadIdx.x < 64) {
    float a = s1[threadIdx.x] + s1[threadIdx.x + 64] + s1[threadIdx.x + 128] + s1[threadIdx.x + 192];
    float b = s2[threadIdx.x] + s2[threadIdx.x + 64] + s2[threadIdx.x + 128] + s2[threadIdx.x + 192];
    atomicAdd(&stats0[c], a);
    atomicAdd(&stats0[64 + c], b);
  }
}

// Fused BN-fold + GEMM: hw' = bf16(((h - m)*rstd*gamma + beta) @ W * dis[node])
__global__ __launch_bounds__(256) void gemm_kernel(const float* __restrict__ h,
    const float* __restrict__ W, const float* __restrict__ gamma,
    const float* __restrict__ beta, const float* __restrict__ stats,
    const float* __restrict__ dis, unsigned short* __restrict__ hwb) {
  __shared__ float Ws[64 * 64];
  __shared__ float HsT[64 * 133];
  __shared__ float sm_a[64], sm_b2[64], sm_bias2[64];
  int tid = threadIdx.x;
  if (tid < 64) {
    float inv_n = 1.0f / (float)NN;
    float m = stats[tid] * inv_n;
    float var = stats[64 + tid] * inv_n - m * m;
    float rstd = rsqrtf(var + BN_EPS);
    float av = gamma[tid] * rstd;
    sm_a[tid] = av;
    sm_b2[tid] = beta[tid] - m * av;
  }
  __syncthreads();
  int nodeBase = blockIdx.x * 128;
  for (int idx = tid; idx < 4096; idx += 256) Ws[idx] = sm_a[idx >> 6] * W[idx];
  for (int idx = tid; idx < 8192; idx += 256) {
    int node = idx >> 6, c = idx & 63;
    int gn = nodeBase + node;
    float v = (gn < NN) ? h[(size_t)gn * CCH + c] : 0.f;
    HsT[c * 133 + node] = v;
  }
  if (tid < 64) {
    float s = 0.f;
    for (int k = 0; k < 64; ++k) s += sm_b2[k] * W[k * 64 + tid];
    sm_bias2[tid] = s;
  }
  __syncthreads();
  int tc = tid & 15;   // channels tc*4..+3
  int tr = tid >> 4;   // nodes tr*8..+7
  float4 bb = *(const float4*)&sm_bias2[tc * 4];
  float acc[8][4];
#pragma unroll
  for (int i = 0; i < 8; ++i) { acc[i][0] = bb.x; acc[i][1] = bb.y; acc[i][2] = bb.z; acc[i][3] = bb.w; }
#pragma unroll 2
  for (int k = 0; k < 64; ++k) {
    float4 wv = *(const float4*)&Ws[k * 64 + tc * 4];
    float4 h0 = *(const float4*)&HsT[k * 133 + tr * 8];
    float4 h1 = *(const float4*)&HsT[k * 133 + tr * 8 + 4];
    float hv[8] = {h0.x, h0.y, h0.z, h0.w, h1.x, h1.y, h1.z, h1.w};
    float wl[4] = {wv.x, wv.y, wv.z, wv.w};
#pragma unroll
    for (int i = 0; i < 8; ++i)
#pragma unroll
      for (int j = 0; j < 4; ++j) acc[i][j] = fmaf(hv[i], wl[j], acc[i][j]);
  }
#pragma unroll
  for (int i = 0; i < 8; ++i) {
    int gn = nodeBase + tr * 8 + i;
    if (gn < NN) {
      float dv = dis[gn];
      uint2 o;
      o.x = f2bf(acc[i][0] * dv) | (f2bf(acc[i][1] * dv) << 16);
      o.y = f2bf(acc[i][2] * dv) | (f2bf(acc[i][3] * dv) << 16);
      *(uint2*)&hwb[(size_t)gn * CCH + tc * 4] = o;
    }
  }
}

// h = relu(h + conv_b + dis_i*(hw'_i + sum_in hw'_src)); fused BN stats.
// Channel-split + XCD affinity; quarter-wave per edge; static node chunks.
__global__ __launch_bounds__(256) void aggregate_kernel(float* __restrict__ h,
    const unsigned short* __restrict__ hwb, const float* __restrict__ dis,
    const int* __restrict__ offs, const int* __restrict__ csr_src,
    const float* __restrict__ conv_b_l, float* __restrict__ stats_next) {
  int tid = threadIdx.x;
  int b = blockIdx.x;
  int half = (b >> 2) & 1;               // xcd = b&7 ; half = xcd>>2
  int subIdx = (b >> 3) * 4 + (b & 3);   // 0..(gridDim/2 - 1) within half
  int wid = subIdx * 4 + (tid >> 6);
  int nwHalf = (gridDim.x >> 1) * 4;
  int chunk = (NN + nwHalf - 1) / nwHalf;
  int lo = wid * chunk;
  int hi = lo + chunk; if (hi > NN) hi = NN;
  int lane = tid & 63;
  int slot = lane >> 4;                  // which edge of the quad
  int l = lane & 15;                     // channel pair within half
  int cbase = half * 32;                 // first channel of this half
  float2 cb = ((const float2*)conv_b_l)[half * 16 + l];
  float ls0 = 0.f, ls1 = 0.f, lq0 = 0.f, lq1 = 0.f;
  for (int i = lo; i < hi; ++i) {
    float a0 = 0.f, a1 = 0.f;
    if (slot == 0) {  // self term (pre-scaled by dis_i)
      unsigned int sv = *(const unsigned int*)&hwb[(size_t)i * CCH + cbase + 2 * l];
      a0 = bf2f(sv & 0xffffu); a1 = bf2f(sv >> 16);
    }
    int e0 = offs[i], e1 = offs[i + 1];
    for (int base = e0; base < e1; base += 8) {
      int iA = base + slot, iB = base + 4 + slot;
      int okA = iA < e1, okB = iB < e1;
      int sA = csr_src[okA ? iA : e1 - 1];
      int sB = csr_src[okB ? iB : e1 - 1];
      unsigned int uA = *(const unsigned int*)&hwb[(size_t)sA * CCH + cbase + 2 * l];
      unsigned int uB = *(const unsigned int*)&hwb[(size_t)sB * CCH + cbase + 2 * l];
      uA = okA ? uA : 0u;
      uB = okB ? uB : 0u;
      a0 += bf2f(uA & 0xffffu) + bf2f(uB & 0xffffu);
      a1 += bf2f(uA >> 16) + bf2f(uB >> 16);
    }
    a0 += __shfl_xor(a0, 16); a0 += __shfl_xor(a0, 32);
    a1 += __shfl_xor(a1, 16); a1 += __shfl_xor(a1, 32);
    if (slot == 0) {
      float2 hv = ((const float2*)h)[(size_t)i * 32 + half * 16 + l];
      float d = dis[i];
      float v0 = hv.x + cb.x + d * a0;
      float v1 = hv.y + cb.y + d * a1;
      v0 = v0 > 0.f ? v0 : 0.f;
      v1 = v1 > 0.f ? v1 : 0.f;
      float2 o; o.x = v0; o.y = v1;
      ((float2*)h)[(size_t)i * 32 + half * 16 + l] = o;
      ls0 += v0; lq0 += v0 * v0; ls1 += v1; lq1 += v1 * v1;
    }
  }
  __shared__ float2 s1[256], s2[256];
  float2 t1; t1.x = ls0; t1.y = ls1;
  float2 t2; t2.x = lq0; t2.y = lq1;
  s1[tid] = t1; s2[tid] = t2;
  __syncthreads();
  if (tid < 32) {  // this block covers 32 channels: cbase + tid
    int pair = tid >> 1, comp = tid & 1;
    float a = 0.f, bb = 0.f;
#pragma unroll
    for (int w = 0; w < 4; ++w) {
      float2 u1 = s1[w * 64 + pair];
      float2 u2 = s2[w * 64 + pair];
      a += comp ? u1.y : u1.x;
      bb += comp ? u2.y : u2.x;
    }
    atomicAdd(&stats_next[cbase + tid], a);
    atomicAdd(&stats_next[64 + cbase + tid], bb);
  }
}

// batch is SORTED: chunked per-wave register accumulation, one atomic per
// graph-boundary per channel.
__global__ __launch_bounds__(256) void pool_kernel(const float* __restrict__ h,
    const int* __restrict__ batch, float* __restrict__ pooled, float* __restrict__ counts) {
  int c = threadIdx.x & 63;
  int wid = (blockIdx.x * blockDim.x + threadIdx.x) >> 6;
  int nw = (gridDim.x * blockDim.x) >> 6;
  int chunk = (NN + nw - 1) / nw;
  int lo = wid * chunk;
  int hi = lo + chunk; if (hi > NN) hi = NN;
  if (lo >= hi) return;
  int g = batch[lo];
  float acc = 0.f, cnt = 0.f;
  for (int i = lo; i < hi; ++i) {
    int gi = batch[i];
    if (gi != g) {
      atomicAdd(&pooled[g * CCH + c], acc);
      if (c == 0) atomicAdd(&counts[g], cnt);
      g = gi; acc = 0.f; cnt = 0.f;
    }
    acc += h[(size_t)i * CCH + c];
    cnt += 1.f;
  }
  atomicAdd(&pooled[g * CCH + c], acc);
  if (c == 0) atomicAdd(&counts[g], cnt);
}

__global__ __launch_bounds__(128) void mlp_kernel(const float* __restrict__ pooled,
    const float* __restrict__ counts, const float* __restrict__ hid_w,
    const float* __restrict__ hid_b, const float* __restrict__ out_w,
    const float* __restrict__ out_b, float* __restrict__ out) {
  int g = blockIdx.x;
  int t = threadIdx.x;  // 128 threads
  __shared__ float p[64], hid[128];
  if (t < 64) {
    float cnt = counts[g];
    cnt = cnt > 1.f ? cnt : 1.f;
    p[t] = pooled[g * CCH + t] / cnt;
  }
  __syncthreads();
  float acc = hid_b[t];
  for (int k = 0; k < 64; ++k) acc = fmaf(p[k], hid_w[k * HID + t], acc);
  acc = acc > 0.f ? acc : 0.f;
  hid[t] = acc;
  __syncthreads();
  if (t < 64) {
    float o = out_b[t];
    for (int j = 0; j < 128; ++j) o = fmaf(hid[j], out_w[j * CCH + t], o);
    out[g * CCH + t] = o;
  }
}

extern "C" void kernel_launch(void* const* d_in, const int* in_sizes, int n_in,
                              void* d_out, int out_size, void* d_ws, size_t ws_size,
                              hipStream_t stream) {
  const int* x       = (const int*)d_in[0];
  const int* ei      = (const int*)d_in[1];
  const int* batch   = (const int*)d_in[2];
  const float* emb   = (const float*)d_in[3];
  const float* gamma = (const float*)d_in[4];
  const float* beta  = (const float*)d_in[5];
  const float* convw = (const float*)d_in[6];
  const float* convb = (const float*)d_in[7];
  const float* hid_w = (const float*)d_in[8];
  const float* hid_b = (const float*)d_in[9];
  const float* out_w = (const float*)d_in[10];
  const float* out_b = (const float*)d_in[11];
  float* out = (float*)d_out;

  float* ws     = (float*)d_ws;
  float* stats  = ws + OFF_STATS;
  float* pooled = ws + OFF_POOLED;
  float* counts = ws + OFF_COUNTS;
  int*   gcur   = (int*)(ws + OFF_GCUR);
  int*   deg    = (int*)(ws + OFF_DEG);
  float* dis    = ws + OFF_DIS;
  int*   offs   = (int*)(ws + OFF_OFFS);
  int*   part   = (int*)(ws + OFF_PART);
  int*   csrsrc = (int*)(ws + OFF_CSRSRC);
  float* h      = ws + OFF_H;
  unsigned short* hwb = (unsigned short*)(ws + OFF_HW);
  unsigned int* staging = (unsigned int*)(ws + OFF_HW);  // aliases hwb (used before gemm)

  hipMemsetAsync(ws, 0, MEMSET_F * sizeof(float), stream);
  init_deg_kernel<<<(NN + 255) / 256, 256, 0, stream>>>(deg);
  count_deg_kernel<<<(NE + 255) / 256, 256, 0, stream>>>(ei, deg);
  scan_blocks_kernel<<<SCAN_NB, 256, 0, stream>>>(deg, offs, part, dis);
  scan_carry_kernel<<<1, 256, 0, stream>>>(part);
  scan_apply_kernel<<<SCAN_NB, 256, 0, stream>>>(part, offs);
  bucket_scatter_kernel<<<(NE + EDGE_CHUNK - 1) / EDGE_CHUNK, 256, 0, stream>>>(ei, offs, gcur, staging);
  bucket_fill_kernel<<<SCAN_NB, 256, 0, stream>>>(staging, offs, csrsrc);
  embed_stats_kernel<<<512, 256, 0, stream>>>(x, emb, h, stats);

  for (int l = 0; l < NLAYER; ++l) {
    gemm_kernel<<<(NN + 127) / 128, 256, 0, stream>>>(h, convw + l * 4096,
                                                      gamma + l * 64, beta + l * 64,
                                                      stats + l * 128, dis, hwb);
    aggregate_kernel<<<2048, 256, 0, stream>>>(h, hwb, dis, offs, csrsrc,
                                               convb + l * 64, stats + (l + 1) * 128);
  }

  pool_kernel<<<128, 256, 0, stream>>>(h, batch, pooled, counts);
  mlp_kernel<<<NG, 128, 0, stream>>>(pooled, counts, hid_w, hid_b, out_w, out_b, out);
}

// Round 8
// 913.896 us; speedup vs baseline: 3.8639x; 1.0256x over previous
//
#include <hip/hip_runtime.h>

#define NN 50000
#define NE 1200000
#define CCH 64
#define NLAYER 8
#define HID 128
#define NG 128
#define BN_EPS 1e-5f
#define SCAN_NB ((NN + 255) / 256)   // 196 blocks / buckets
#define EDGE_CHUNK 8192              // edges per bucket_scatter block

// ---- workspace layout (offsets in floats) ----
// [stats(9*128) | pooled(128*64) | counts(128) | gcur(256)] <- zeroed by one memsetAsync
enum : size_t {
  OFF_STATS  = 0,
  OFF_POOLED = 1152,
  OFF_COUNTS = 9344,
  OFF_GCUR   = 9472,       // 196 bucket cursors (ints)
  MEMSET_F   = 9728,
  OFF_DEG    = 9728,       // int[N]
  OFF_DIS    = 59728,
  OFF_OFFS   = 109728,     // N+1 (+pad)
  OFF_PART   = 159732,     // 256 block partials
  OFF_CSRSRC = 159988,     // int[E]
  OFF_H      = 1359988,    // float[N*64]
  OFF_HW     = 4559988,    // ushort[4][N][16] (bf16 channel slabs); staging aliases
  WS_FLOATS  = 6159988
};

__device__ __forceinline__ float bf2f(unsigned int hs) {
  union { unsigned int u; float f; } c; c.u = hs << 16; return c.f;
}
__device__ __forceinline__ unsigned int f2bf(float x) {
  union { float f; unsigned int u; } c; c.f = x;
  return (c.u + 0x7fffu + ((c.u >> 16) & 1u)) >> 16;  // RNE
}

__global__ void init_deg_kernel(int* __restrict__ deg) {
  int i = blockIdx.x * blockDim.x + threadIdx.x;
  if (i < NN) deg[i] = 1;  // self-loop
}

__global__ void count_deg_kernel(const int* __restrict__ ei, int* __restrict__ deg) {
  int e = blockIdx.x * blockDim.x + threadIdx.x;
  if (e < NE) atomicAdd(&deg[ei[NE + e]], 1);
}

// Per-block exclusive scan of (deg-1); also computes dis = rsqrt(deg).
__global__ __launch_bounds__(256) void scan_blocks_kernel(const int* __restrict__ deg,
    int* __restrict__ offs, int* __restrict__ partials, float* __restrict__ dis) {
  int i = blockIdx.x * 256 + threadIdx.x;
  int v = 0;
  if (i < NN) {
    int d = deg[i];
    v = d - 1;
    dis[i] = rsqrtf((float)d);
  }
  __shared__ int sm[256];
  sm[threadIdx.x] = v;
  __syncthreads();
  for (int d = 1; d < 256; d <<= 1) {
    int add = (threadIdx.x >= d) ? sm[threadIdx.x - d] : 0;
    __syncthreads();
    sm[threadIdx.x] += add;
    __syncthreads();
  }
  if (i < NN) offs[i] = sm[threadIdx.x] - v;  // exclusive within block
  if (threadIdx.x == 255) partials[blockIdx.x] = sm[255];
}

__global__ __launch_bounds__(256) void scan_carry_kernel(int* __restrict__ partials) {
  int t = threadIdx.x;
  int v = (t < SCAN_NB) ? partials[t] : 0;
  __shared__ int sm[256];
  sm[t] = v;
  __syncthreads();
  for (int d = 1; d < 256; d <<= 1) {
    int add = (t >= d) ? sm[t - d] : 0;
    __syncthreads();
    sm[t] += add;
    __syncthreads();
  }
  if (t < SCAN_NB) partials[t] = sm[t] - v;  // exclusive carry per block
}

__global__ __launch_bounds__(256) void scan_apply_kernel(const int* __restrict__ partials,
    int* __restrict__ offs) {
  int i = blockIdx.x * 256 + threadIdx.x;
  if (i < NN) offs[i] += partials[blockIdx.x];
  if (i == 0) offs[NN] = NE;
}

// ---- CSR build phase A: bucket edges by dst>>8 into staging (packed u32).
__global__ __launch_bounds__(256) void bucket_scatter_kernel(const int* __restrict__ ei,
    const int* __restrict__ offs, int* __restrict__ gcur, unsigned int* __restrict__ staging) {
  __shared__ int bcnt[SCAN_NB];
  __shared__ int bbase[SCAN_NB];
  int tid = threadIdx.x;
  int lo = blockIdx.x * EDGE_CHUNK;
  int hi = lo + EDGE_CHUNK; if (hi > NE) hi = NE;
  for (int b = tid; b < SCAN_NB; b += 256) bcnt[b] = 0;
  __syncthreads();
  for (int e = lo + tid; e < hi; e += 256)
    atomicAdd(&bcnt[ei[NE + e] >> 8], 1);
  __syncthreads();
  for (int b = tid; b < SCAN_NB; b += 256) {
    int c = bcnt[b];
    bbase[b] = c ? (offs[b << 8] + atomicAdd(&gcur[b], c)) : 0;
    bcnt[b] = 0;
  }
  __syncthreads();
  for (int e = lo + tid; e < hi; e += 256) {
    int src = ei[e], dst = ei[NE + e];
    int b = dst >> 8;
    int p = bbase[b] + atomicAdd(&bcnt[b], 1);
    staging[p] = ((unsigned int)(dst & 255) << 16) | (unsigned int)src;
  }
}

// ---- CSR build phase B: one block per bucket; LDS cursors; final placement.
__global__ __launch_bounds__(256) void bucket_fill_kernel(const unsigned int* __restrict__ staging,
    const int* __restrict__ offs, int* __restrict__ csr_src) {
  __shared__ int ncur[256];
  int b = blockIdx.x;
  int nodeBase = b << 8;
  int tid = threadIdx.x;
  int nHi = nodeBase + 256; if (nHi > NN) nHi = NN;
  int nLoc = nHi - nodeBase;
  if (tid < nLoc) ncur[tid] = offs[nodeBase + tid];
  __syncthreads();
  int r0 = offs[nodeBase], r1 = offs[nHi];
  for (int e = r0 + tid; e < r1; e += 256) {
    unsigned int v = staging[e];
    int p = atomicAdd(&ncur[v >> 16], 1);
    csr_src[p] = (int)(v & 0xffffu);
  }
}

// h = emb[x]; also accumulate BN stats for layer 0
__global__ __launch_bounds__(256) void embed_stats_kernel(const int* __restrict__ x,
    const float* __restrict__ emb, float* __restrict__ h, float* __restrict__ stats0) {
  int c = threadIdx.x & 63;
  int wave = (blockIdx.x * blockDim.x + threadIdx.x) >> 6;
  int nw = (gridDim.x * blockDim.x) >> 6;
  float ls = 0.f, lq = 0.f;
  for (int i = wave; i < NN; i += nw) {
    float v = emb[x[i] * CCH + c];
    h[(size_t)i * CCH + c] = v;
    ls += v; lq += v * v;
  }
  __shared__ float s1[256], s2[256];
  s1[threadIdx.x] = ls; s2[threadIdx.x] = lq;
  __syncthreads();
  if (threadIdx.x < 64) {
    float a = s1[threadIdx.x] + s1[threadIdx.x + 64] + s1[threadIdx.x + 128] + s1[threadIdx.x + 192];
    float b = s2[threadIdx.x] + s2[threadIdx.x + 64] + s2[threadIdx.x + 128] + s2[threadIdx.x + 192];
    atomicAdd(&stats0[c], a);
    atomicAdd(&stats0[64 + c], b);
  }
}

// Fused BN-fold + GEMM: hw' = bf16(((h-m)*rstd*gamma+beta) @ W * dis[node]),
// written in channel-slab layout: hwb[slab][node][16ch], slab = ch/16.
__global__ __launch_bounds__(256) void gemm_kernel(const float* __restrict__ h,
    const float* __restrict__ W, const float* __restrict__ gamma,
    const float* __restrict__ beta, const float* __restrict__ stats,
    const float* __restrict__ dis, unsigned short* __restrict__ hwb) {
  __shared__ float Ws[64 * 64];
  __shared__ float HsT[64 * 133];
  __shared__ float sm_a[64], sm_b2[64], sm_bias2[64];
  int tid = threadIdx.x;
  if (tid < 64) {
    float inv_n = 1.0f / (float)NN;
    float m = stats[tid] * inv_n;
    float var = stats[64 + tid] * inv_n - m * m;
    float rstd = rsqrtf(var + BN_EPS);
    float av = gamma[tid] * rstd;
    sm_a[tid] = av;
    sm_b2[tid] = beta[tid] - m * av;
  }
  __syncthreads();
  int nodeBase = blockIdx.x * 128;
  for (int idx = tid; idx < 4096; idx += 256) Ws[idx] = sm_a[idx >> 6] * W[idx];
  for (int idx = tid; idx < 8192; idx += 256) {
    int node = idx >> 6, c = idx & 63;
    int gn = nodeBase + node;
    float v = (gn < NN) ? h[(size_t)gn * CCH + c] : 0.f;
    HsT[c * 133 + node] = v;
  }
  if (tid < 64) {
    float s = 0.f;
    for (int k = 0; k < 64; ++k) s += sm_b2[k] * W[k * 64 + tid];
    sm_bias2[tid] = s;
  }
  __syncthreads();
  int tc = tid & 15;   // channels tc*4..+3
  int tr = tid >> 4;   // nodes tr*8..+7
  float4 bb = *(const float4*)&sm_bias2[tc * 4];
  float acc[8][4];
#pragma unroll
  for (int i = 0; i < 8; ++i) { acc[i][0] = bb.x; acc[i][1] = bb.y; acc[i][2] = bb.z; acc[i][3] = bb.w; }
#pragma unroll 2
  for (int k = 0; k < 64; ++k) {
    float4 wv = *(const float4*)&Ws[k * 64 + tc * 4];
    float4 h0 = *(const float4*)&HsT[k * 133 + tr * 8];
    float4 h1 = *(const float4*)&HsT[k * 133 + tr * 8 + 4];
    float hv[8] = {h0.x, h0.y, h0.z, h0.w, h1.x, h1.y, h1.z, h1.w};
    float wl[4] = {wv.x, wv.y, wv.z, wv.w};
#pragma unroll
    for (int i = 0; i < 8; ++i)
#pragma unroll
      for (int j = 0; j < 4; ++j) acc[i][j] = fmaf(hv[i], wl[j], acc[i][j]);
  }
  unsigned short* slabp = hwb + (size_t)(tc >> 2) * NN * 16;
  int coff = (tc & 3) * 4;
#pragma unroll
  for (int i = 0; i < 8; ++i) {
    int gn = nodeBase + tr * 8 + i;
    if (gn < NN) {
      float dv = dis[gn];
      uint2 o;
      o.x = f2bf(acc[i][0] * dv) | (f2bf(acc[i][1] * dv) << 16);
      o.y = f2bf(acc[i][2] * dv) | (f2bf(acc[i][3] * dv) << 16);
      *(uint2*)&slabp[(size_t)gn * 16 + coff] = o;
    }
  }
}

// h = relu(h + conv_b + dis_i*(hw'_i + sum_in hw'_src)); fused BN stats.
// 4-way channel-slab split with XCD affinity: slab = blockIdx&3 (XCDs k and
// k+4 share slab k, splitting nodes). Each XCD's gather target is a 1.6MB
// L2-resident slab. 8 lanes (ushort2 each) per edge = 32B; 16 edges in
// flight per wave (slot = lane>>3, A/B unroll).
__global__ __launch_bounds__(256) void aggregate_kernel(float* __restrict__ h,
    const unsigned short* __restrict__ hwb, const float* __restrict__ dis,
    const int* __restrict__ offs, const int* __restrict__ csr_src,
    const float* __restrict__ conv_b_l, float* __restrict__ stats_next) {
  int tid = threadIdx.x;
  int b = blockIdx.x;
  int slab = b & 3;                          // XCD = b&7; slab = XCD&3
  int subIdx = (b >> 3) * 2 + ((b >> 2) & 1);  // block index among those sharing slab
  int wid = subIdx * 4 + (tid >> 6);
  int nwSlab = (gridDim.x >> 2) * 4;         // waves per slab
  int chunk = (NN + nwSlab - 1) / nwSlab;
  int lo = wid * chunk;
  int hi = lo + chunk; if (hi > NN) hi = NN;
  int lane = tid & 63;
  int slot = lane >> 3;                      // which edge of the octet
  int l = lane & 7;                          // channel pair within slab (16 ch)
  int cbase = slab * 16;
  const unsigned short* slabp = hwb + (size_t)slab * NN * 16;
  float2 cb = ((const float2*)conv_b_l)[slab * 8 + l];
  float ls0 = 0.f, ls1 = 0.f, lq0 = 0.f, lq1 = 0.f;
  for (int i = lo; i < hi; ++i) {
    float a0 = 0.f, a1 = 0.f;
    if (slot == 0) {  // self term (pre-scaled by dis_i)
      unsigned int sv = *(const unsigned int*)&slabp[(size_t)i * 16 + 2 * l];
      a0 = bf2f(sv & 0xffffu); a1 = bf2f(sv >> 16);
    }
    int e0 = offs[i], e1 = offs[i + 1];
    for (int base = e0; base < e1; base += 16) {
      int iA = base + slot, iB = base + 8 + slot;
      int okA = iA < e1, okB = iB < e1;
      int sA = csr_src[okA ? iA : e1 - 1];
      int sB = csr_src[okB ? iB : e1 - 1];
      unsigned int uA = *(const unsigned int*)&slabp[(size_t)sA * 16 + 2 * l];
      unsigned int uB = *(const unsigned int*)&slabp[(size_t)sB * 16 + 2 * l];
      uA = okA ? uA : 0u;
      uB = okB ? uB : 0u;
      a0 += bf2f(uA & 0xffffu) + bf2f(uB & 0xffffu);
      a1 += bf2f(uA >> 16) + bf2f(uB >> 16);
    }
    a0 += __shfl_xor(a0, 8); a0 += __shfl_xor(a0, 16); a0 += __shfl_xor(a0, 32);
    a1 += __shfl_xor(a1, 8); a1 += __shfl_xor(a1, 16); a1 += __shfl_xor(a1, 32);
    if (slot == 0) {
      float2 hv = ((const float2*)h)[(size_t)i * 32 + slab * 8 + l];
      float d = dis[i];
      float v0 = hv.x + cb.x + d * a0;
      float v1 = hv.y + cb.y + d * a1;
      v0 = v0 > 0.f ? v0 : 0.f;
      v1 = v1 > 0.f ? v1 : 0.f;
      float2 o; o.x = v0; o.y = v1;
      ((float2*)h)[(size_t)i * 32 + slab * 8 + l] = o;
      ls0 += v0; lq0 += v0 * v0; ls1 += v1; lq1 += v1 * v1;
    }
  }
  __shared__ float2 s1[256], s2[256];
  float2 t1; t1.x = ls0; t1.y = ls1;
  float2 t2; t2.x = lq0; t2.y = lq1;
  s1[tid] = t1; s2[tid] = t2;
  __syncthreads();
  if (tid < 16) {  // this block covers 16 channels: cbase + tid
    int pair = tid >> 1, comp = tid & 1;   // slot-0 lanes 0..7 of each wave
    float a = 0.f, bb = 0.f;
#pragma unroll
    for (int w = 0; w < 4; ++w) {
      float2 u1 = s1[w * 64 + pair];
      float2 u2 = s2[w * 64 + pair];
      a += comp ? u1.y : u1.x;
      bb += comp ? u2.y : u2.x;
    }
    atomicAdd(&stats_next[cbase + tid], a);
    atomicAdd(&stats_next[64 + cbase + tid], bb);
  }
}

// batch is SORTED: chunked per-wave register accumulation, one atomic per
// graph-boundary per channel.
__global__ __launch_bounds__(256) void pool_kernel(const float* __restrict__ h,
    const int* __restrict__ batch, float* __restrict__ pooled, float* __restrict__ counts) {
  int c = threadIdx.x & 63;
  int wid = (blockIdx.x * blockDim.x + threadIdx.x) >> 6;
  int nw = (gridDim.x * blockDim.x) >> 6;
  int chunk = (NN + nw - 1) / nw;
  int lo = wid * chunk;
  int hi = lo + chunk; if (hi > NN) hi = NN;
  if (lo >= hi) return;
  int g = batch[lo];
  float acc = 0.f, cnt = 0.f;
  for (int i = lo; i < hi; ++i) {
    int gi = batch[i];
    if (gi != g) {
      atomicAdd(&pooled[g * CCH + c], acc);
      if (c == 0) atomicAdd(&counts[g], cnt);
      g = gi; acc = 0.f; cnt = 0.f;
    }
    acc += h[(size_t)i * CCH + c];
    cnt += 1.f;
  }
  atomicAdd(&pooled[g * CCH + c], acc);
  if (c == 0) atomicAdd(&counts[g], cnt);
}

__global__ __launch_bounds__(128) void mlp_kernel(const float* __restrict__ pooled,
    const float* __restrict__ counts, const float* __restrict__ hid_w,
    const float* __restrict__ hid_b, const float* __restrict__ out_w,
    const float* __restrict__ out_b, float* __restrict__ out) {
  int g = blockIdx.x;
  int t = threadIdx.x;  // 128 threads
  __shared__ float p[64], hid[128];
  if (t < 64) {
    float cnt = counts[g];
    cnt = cnt > 1.f ? cnt : 1.f;
    p[t] = pooled[g * CCH + t] / cnt;
  }
  __syncthreads();
  float acc = hid_b[t];
  for (int k = 0; k < 64; ++k) acc = fmaf(p[k], hid_w[k * HID + t], acc);
  acc = acc > 0.f ? acc : 0.f;
  hid[t] = acc;
  __syncthreads();
  if (t < 64) {
    float o = out_b[t];
    for (int j = 0; j < 128; ++j) o = fmaf(hid[j], out_w[j * CCH + t], o);
    out[g * CCH + t] = o;
  }
}

extern "C" void kernel_launch(void* const* d_in, const int* in_sizes, int n_in,
                              void* d_out, int out_size, void* d_ws, size_t ws_size,
                              hipStream_t stream) {
  const int* x       = (const int*)d_in[0];
  const int* ei      = (const int*)d_in[1];
  const int* batch   = (const int*)d_in[2];
  const float* emb   = (const float*)d_in[3];
  const float* gamma = (const float*)d_in[4];
  const float* beta  = (const float*)d_in[5];
  const float* convw = (const float*)d_in[6];
  const float* convb = (const float*)d_in[7];
  const float* hid_w = (const float*)d_in[8];
  const float* hid_b = (const float*)d_in[9];
  const float* out_w = (const float*)d_in[10];
  const float* out_b = (const float*)d_in[11];
  float* out = (float*)d_out;

  float* ws     = (float*)d_ws;
  float* stats  = ws + OFF_STATS;
  float* pooled = ws + OFF_POOLED;
  float* counts = ws + OFF_COUNTS;
  int*   gcur   = (int*)(ws + OFF_GCUR);
  int*   deg    = (int*)(ws + OFF_DEG);
  float* dis    = ws + OFF_DIS;
  int*   offs   = (int*)(ws + OFF_OFFS);
  int*   part   = (int*)(ws + OFF_PART);
  int*   csrsrc = (int*)(ws + OFF_CSRSRC);
  float* h      = ws + OFF_H;
  unsigned short* hwb = (unsigned short*)(ws + OFF_HW);
  unsigned int* staging = (unsigned int*)(ws + OFF_HW);  // aliases hwb (used before gemm)

  hipMemsetAsync(ws, 0, MEMSET_F * sizeof(float), stream);
  init_deg_kernel<<<(NN + 255) / 256, 256, 0, stream>>>(deg);
  count_deg_kernel<<<(NE + 255) / 256, 256, 0, stream>>>(ei, deg);
  scan_blocks_kernel<<<SCAN_NB, 256, 0, stream>>>(deg, offs, part, dis);
  scan_carry_kernel<<<1, 256, 0, stream>>>(part);
  scan_apply_kernel<<<SCAN_NB, 256, 0, stream>>>(part, offs);
  bucket_scatter_kernel<<<(NE + EDGE_CHUNK - 1) / EDGE_CHUNK, 256, 0, stream>>>(ei, offs, gcur, staging);
  bucket_fill_kernel<<<SCAN_NB, 256, 0, stream>>>(staging, offs, csrsrc);
  embed_stats_kernel<<<512, 256, 0, stream>>>(x, emb, h, stats);

  for (int l = 0; l < NLAYER; ++l) {
    gemm_kernel<<<(NN + 127) / 128, 256, 0, stream>>>(h, convw + l * 4096,
                                                      gamma + l * 64, beta + l * 64,
                                                      stats + l * 128, dis, hwb);
    aggregate_kernel<<<2048, 256, 0, stream>>>(h, hwb, dis, offs, csrsrc,
                                               convb + l * 64, stats + (l + 1) * 128);
  }

  pool_kernel<<<128, 256, 0, stream>>>(h, batch, pooled, counts);
  mlp_kernel<<<NG, 128, 0, stream>>>(pooled, counts, hid_w, hid_b, out_w, out_b, out);
}

// Round 9
// 854.503 us; speedup vs baseline: 4.1325x; 1.0695x over previous
//
#include <hip/hip_runtime.h>

#define NN 50000
#define NE 1200000
#define CCH 64
#define NLAYER 8
#define HID 128
#define NG 128
#define BN_EPS 1e-5f
#define SCAN_NB ((NN + 255) / 256)   // 196 blocks / buckets
#define EDGE_CHUNK 8192              // edges per bucket_scatter block

// ---- workspace layout (offsets in floats) ----
// [stats(9*128) | pooled(128*64) | counts(128) | gcur(256)] <- zeroed by one memsetAsync
enum : size_t {
  OFF_STATS  = 0,
  OFF_POOLED = 1152,
  OFF_COUNTS = 9344,
  OFF_GCUR   = 9472,       // 196 bucket cursors (ints)
  MEMSET_F   = 9728,
  OFF_DEG    = 9728,       // int[N]
  OFF_DIS    = 59728,
  OFF_OFFS   = 109728,     // N+1 (+pad)
  OFF_PART   = 159732,     // 256 block partials
  OFF_CSRSRC = 159988,     // int[E]
  OFF_H      = 1359988,    // float[N*64]
  OFF_HW     = 4559988,    // ushort[4][N][16] (bf16 channel slabs); staging aliases
  WS_FLOATS  = 6159988
};

__device__ __forceinline__ float bf2f(unsigned int hs) {
  union { unsigned int u; float f; } c; c.u = hs << 16; return c.f;
}
__device__ __forceinline__ unsigned int f2bf(float x) {
  union { float f; unsigned int u; } c; c.f = x;
  return (c.u + 0x7fffu + ((c.u >> 16) & 1u)) >> 16;  // RNE
}

__global__ void init_deg_kernel(int* __restrict__ deg) {
  int i = blockIdx.x * blockDim.x + threadIdx.x;
  if (i < NN) deg[i] = 1;  // self-loop
}

__global__ void count_deg_kernel(const int* __restrict__ ei, int* __restrict__ deg) {
  int e = blockIdx.x * blockDim.x + threadIdx.x;
  if (e < NE) atomicAdd(&deg[ei[NE + e]], 1);
}

// Per-block exclusive scan of (deg-1); also computes dis = rsqrt(deg).
__global__ __launch_bounds__(256) void scan_blocks_kernel(const int* __restrict__ deg,
    int* __restrict__ offs, int* __restrict__ partials, float* __restrict__ dis) {
  int i = blockIdx.x * 256 + threadIdx.x;
  int v = 0;
  if (i < NN) {
    int d = deg[i];
    v = d - 1;
    dis[i] = rsqrtf((float)d);
  }
  __shared__ int sm[256];
  sm[threadIdx.x] = v;
  __syncthreads();
  for (int d = 1; d < 256; d <<= 1) {
    int add = (threadIdx.x >= d) ? sm[threadIdx.x - d] : 0;
    __syncthreads();
    sm[threadIdx.x] += add;
    __syncthreads();
  }
  if (i < NN) offs[i] = sm[threadIdx.x] - v;  // exclusive within block
  if (threadIdx.x == 255) partials[blockIdx.x] = sm[255];
}

__global__ __launch_bounds__(256) void scan_carry_kernel(int* __restrict__ partials) {
  int t = threadIdx.x;
  int v = (t < SCAN_NB) ? partials[t] : 0;
  __shared__ int sm[256];
  sm[t] = v;
  __syncthreads();
  for (int d = 1; d < 256; d <<= 1) {
    int add = (t >= d) ? sm[t - d] : 0;
    __syncthreads();
    sm[t] += add;
    __syncthreads();
  }
  if (t < SCAN_NB) partials[t] = sm[t] - v;  // exclusive carry per block
}

__global__ __launch_bounds__(256) void scan_apply_kernel(const int* __restrict__ partials,
    int* __restrict__ offs) {
  int i = blockIdx.x * 256 + threadIdx.x;
  if (i < NN) offs[i] += partials[blockIdx.x];
  if (i == 0) offs[NN] = NE;
}

// ---- CSR build phase A: bucket edges by dst>>8 into staging (packed u32).
__global__ __launch_bounds__(256) void bucket_scatter_kernel(const int* __restrict__ ei,
    const int* __restrict__ offs, int* __restrict__ gcur, unsigned int* __restrict__ staging) {
  __shared__ int bcnt[SCAN_NB];
  __shared__ int bbase[SCAN_NB];
  int tid = threadIdx.x;
  int lo = blockIdx.x * EDGE_CHUNK;
  int hi = lo + EDGE_CHUNK; if (hi > NE) hi = NE;
  for (int b = tid; b < SCAN_NB; b += 256) bcnt[b] = 0;
  __syncthreads();
  for (int e = lo + tid; e < hi; e += 256)
    atomicAdd(&bcnt[ei[NE + e] >> 8], 1);
  __syncthreads();
  for (int b = tid; b < SCAN_NB; b += 256) {
    int c = bcnt[b];
    bbase[b] = c ? (offs[b << 8] + atomicAdd(&gcur[b], c)) : 0;
    bcnt[b] = 0;
  }
  __syncthreads();
  for (int e = lo + tid; e < hi; e += 256) {
    int src = ei[e], dst = ei[NE + e];
    int b = dst >> 8;
    int p = bbase[b] + atomicAdd(&bcnt[b], 1);
    staging[p] = ((unsigned int)(dst & 255) << 16) | (unsigned int)src;
  }
}

// ---- CSR build phase B: one block per bucket; LDS cursors; final placement.
__global__ __launch_bounds__(256) void bucket_fill_kernel(const unsigned int* __restrict__ staging,
    const int* __restrict__ offs, int* __restrict__ csr_src) {
  __shared__ int ncur[256];
  int b = blockIdx.x;
  int nodeBase = b << 8;
  int tid = threadIdx.x;
  int nHi = nodeBase + 256; if (nHi > NN) nHi = NN;
  int nLoc = nHi - nodeBase;
  if (tid < nLoc) ncur[tid] = offs[nodeBase + tid];
  __syncthreads();
  int r0 = offs[nodeBase], r1 = offs[nHi];
  for (int e = r0 + tid; e < r1; e += 256) {
    unsigned int v = staging[e];
    int p = atomicAdd(&ncur[v >> 16], 1);
    csr_src[p] = (int)(v & 0xffffu);
  }
}

// h = emb[x]; also accumulate BN stats for layer 0
__global__ __launch_bounds__(256) void embed_stats_kernel(const int* __restrict__ x,
    const float* __restrict__ emb, float* __restrict__ h, float* __restrict__ stats0) {
  int c = threadIdx.x & 63;
  int wave = (blockIdx.x * blockDim.x + threadIdx.x) >> 6;
  int nw = (gridDim.x * blockDim.x) >> 6;
  float ls = 0.f, lq = 0.f;
  for (int i = wave; i < NN; i += nw) {
    float v = emb[x[i] * CCH + c];
    h[(size_t)i * CCH + c] = v;
    ls += v; lq += v * v;
  }
  __shared__ float s1[256], s2[256];
  s1[threadIdx.x] = ls; s2[threadIdx.x] = lq;
  __syncthreads();
  if (threadIdx.x < 64) {
    float a = s1[threadIdx.x] + s1[threadIdx.x + 64] + s1[threadIdx.x + 128] + s1[threadIdx.x + 192];
    float b = s2[threadIdx.x] + s2[threadIdx.x + 64] + s2[threadIdx.x + 128] + s2[threadIdx.x + 192];
    atomicAdd(&stats0[c], a);
    atomicAdd(&stats0[64 + c], b);
  }
}

// Fused BN-fold + GEMM: hw' = bf16(((h-m)*rstd*gamma+beta) @ W * dis[node]),
// written in channel-slab layout: hwb[slab][node][16ch], slab = ch/16.
__global__ __launch_bounds__(256) void gemm_kernel(const float* __restrict__ h,
    const float* __restrict__ W, const float* __restrict__ gamma,
    const float* __restrict__ beta, const float* __restrict__ stats,
    const float* __restrict__ dis, unsigned short* __restrict__ hwb) {
  __shared__ float Ws[64 * 64];
  __shared__ float HsT[64 * 133];
  __shared__ float sm_a[64], sm_b2[64], sm_bias2[64];
  int tid = threadIdx.x;
  if (tid < 64) {
    float inv_n = 1.0f / (float)NN;
    float m = stats[tid] * inv_n;
    float var = stats[64 + tid] * inv_n - m * m;
    float rstd = rsqrtf(var + BN_EPS);
    float av = gamma[tid] * rstd;
    sm_a[tid] = av;
    sm_b2[tid] = beta[tid] - m * av;
  }
  __syncthreads();
  int nodeBase = blockIdx.x * 128;
  for (int idx = tid; idx < 4096; idx += 256) Ws[idx] = sm_a[idx >> 6] * W[idx];
  for (int idx = tid; idx < 8192; idx += 256) {
    int node = idx >> 6, c = idx & 63;
    int gn = nodeBase + node;
    float v = (gn < NN) ? h[(size_t)gn * CCH + c] : 0.f;
    HsT[c * 133 + node] = v;
  }
  if (tid < 64) {
    float s = 0.f;
    for (int k = 0; k < 64; ++k) s += sm_b2[k] * W[k * 64 + tid];
    sm_bias2[tid] = s;
  }
  __syncthreads();
  int tc = tid & 15;   // channels tc*4..+3
  int tr = tid >> 4;   // nodes tr*8..+7
  float4 bb = *(const float4*)&sm_bias2[tc * 4];
  float acc[8][4];
#pragma unroll
  for (int i = 0; i < 8; ++i) { acc[i][0] = bb.x; acc[i][1] = bb.y; acc[i][2] = bb.z; acc[i][3] = bb.w; }
#pragma unroll 2
  for (int k = 0; k < 64; ++k) {
    float4 wv = *(const float4*)&Ws[k * 64 + tc * 4];
    float4 h0 = *(const float4*)&HsT[k * 133 + tr * 8];
    float4 h1 = *(const float4*)&HsT[k * 133 + tr * 8 + 4];
    float hv[8] = {h0.x, h0.y, h0.z, h0.w, h1.x, h1.y, h1.z, h1.w};
    float wl[4] = {wv.x, wv.y, wv.z, wv.w};
#pragma unroll
    for (int i = 0; i < 8; ++i)
#pragma unroll
      for (int j = 0; j < 4; ++j) acc[i][j] = fmaf(hv[i], wl[j], acc[i][j]);
  }
  unsigned short* slabp = hwb + (size_t)(tc >> 2) * NN * 16;
  int coff = (tc & 3) * 4;
#pragma unroll
  for (int i = 0; i < 8; ++i) {
    int gn = nodeBase + tr * 8 + i;
    if (gn < NN) {
      float dv = dis[gn];
      uint2 o;
      o.x = f2bf(acc[i][0] * dv) | (f2bf(acc[i][1] * dv) << 16);
      o.y = f2bf(acc[i][2] * dv) | (f2bf(acc[i][3] * dv) << 16);
      *(uint2*)&slabp[(size_t)gn * 16 + coff] = o;
    }
  }
}

// h = relu(h + conv_b + dis_i*(hw'_i + sum_in hw'_src)); fused BN stats.
// 4-way channel-slab split with XCD affinity (slab = blockIdx&3; each XCD's
// 1.6MB slab is L2-resident). 8 lanes (ushort2) per edge; FOUR independent
// octets A/B/C/D per iteration -> 32 edges in flight, one {csr->gather}
// round-trip covers deg<=32 (~95% of nodes).
__global__ __launch_bounds__(256) void aggregate_kernel(float* __restrict__ h,
    const unsigned short* __restrict__ hwb, const float* __restrict__ dis,
    const int* __restrict__ offs, const int* __restrict__ csr_src,
    const float* __restrict__ conv_b_l, float* __restrict__ stats_next) {
  int tid = threadIdx.x;
  int b = blockIdx.x;
  int slab = b & 3;                          // XCD = b&7; slab = XCD&3
  int subIdx = (b >> 3) * 2 + ((b >> 2) & 1);  // block index among those sharing slab
  int wid = subIdx * 4 + (tid >> 6);
  int nwSlab = (gridDim.x >> 2) * 4;         // waves per slab
  int chunk = (NN + nwSlab - 1) / nwSlab;
  int lo = wid * chunk;
  int hi = lo + chunk; if (hi > NN) hi = NN;
  int lane = tid & 63;
  int slot = lane >> 3;                      // which edge of the octet
  int l = lane & 7;                          // channel pair within slab (16 ch)
  int cbase = slab * 16;
  const unsigned short* slabp = hwb + (size_t)slab * NN * 16;
  float2 cb = ((const float2*)conv_b_l)[slab * 8 + l];
  float ls0 = 0.f, ls1 = 0.f, lq0 = 0.f, lq1 = 0.f;
  for (int i = lo; i < hi; ++i) {
    float a0 = 0.f, a1 = 0.f;
    if (slot == 0) {  // self term (pre-scaled by dis_i)
      unsigned int sv = *(const unsigned int*)&slabp[(size_t)i * 16 + 2 * l];
      a0 = bf2f(sv & 0xffffu); a1 = bf2f(sv >> 16);
    }
    int e0 = offs[i], e1 = offs[i + 1];
    for (int base = e0; base < e1; base += 32) {
      int iA = base + slot, iB = iA + 8, iC = iA + 16, iD = iA + 24;
      int okA = iA < e1, okB = iB < e1, okC = iC < e1, okD = iD < e1;
      int sA = csr_src[okA ? iA : e1 - 1];
      int sB = csr_src[okB ? iB : e1 - 1];
      int sC = csr_src[okC ? iC : e1 - 1];
      int sD = csr_src[okD ? iD : e1 - 1];
      unsigned int uA = *(const unsigned int*)&slabp[(size_t)sA * 16 + 2 * l];
      unsigned int uB = *(const unsigned int*)&slabp[(size_t)sB * 16 + 2 * l];
      unsigned int uC = *(const unsigned int*)&slabp[(size_t)sC * 16 + 2 * l];
      unsigned int uD = *(const unsigned int*)&slabp[(size_t)sD * 16 + 2 * l];
      uA = okA ? uA : 0u;
      uB = okB ? uB : 0u;
      uC = okC ? uC : 0u;
      uD = okD ? uD : 0u;
      a0 += bf2f(uA & 0xffffu) + bf2f(uB & 0xffffu) + bf2f(uC & 0xffffu) + bf2f(uD & 0xffffu);
      a1 += bf2f(uA >> 16) + bf2f(uB >> 16) + bf2f(uC >> 16) + bf2f(uD >> 16);
    }
    a0 += __shfl_xor(a0, 8); a0 += __shfl_xor(a0, 16); a0 += __shfl_xor(a0, 32);
    a1 += __shfl_xor(a1, 8); a1 += __shfl_xor(a1, 16); a1 += __shfl_xor(a1, 32);
    if (slot == 0) {
      float2 hv = ((const float2*)h)[(size_t)i * 32 + slab * 8 + l];
      float d = dis[i];
      float v0 = hv.x + cb.x + d * a0;
      float v1 = hv.y + cb.y + d * a1;
      v0 = v0 > 0.f ? v0 : 0.f;
      v1 = v1 > 0.f ? v1 : 0.f;
      float2 o; o.x = v0; o.y = v1;
      ((float2*)h)[(size_t)i * 32 + slab * 8 + l] = o;
      ls0 += v0; lq0 += v0 * v0; ls1 += v1; lq1 += v1 * v1;
    }
  }
  __shared__ float2 s1[256], s2[256];
  float2 t1; t1.x = ls0; t1.y = ls1;
  float2 t2; t2.x = lq0; t2.y = lq1;
  s1[tid] = t1; s2[tid] = t2;
  __syncthreads();
  if (tid < 16) {  // this block covers 16 channels: cbase + tid
    int pair = tid >> 1, comp = tid & 1;   // slot-0 lanes 0..7 of each wave
    float a = 0.f, bb = 0.f;
#pragma unroll
    for (int w = 0; w < 4; ++w) {
      float2 u1 = s1[w * 64 + pair];
      float2 u2 = s2[w * 64 + pair];
      a += comp ? u1.y : u1.x;
      bb += comp ? u2.y : u2.x;
    }
    atomicAdd(&stats_next[cbase + tid], a);
    atomicAdd(&stats_next[64 + cbase + tid], bb);
  }
}

// batch is SORTED: chunked per-wave register accumulation, one atomic per
// graph-boundary per channel.
__global__ __launch_bounds__(256) void pool_kernel(const float* __restrict__ h,
    const int* __restrict__ batch, float* __restrict__ pooled, float* __restrict__ counts) {
  int c = threadIdx.x & 63;
  int wid = (blockIdx.x * blockDim.x + threadIdx.x) >> 6;
  int nw = (gridDim.x * blockDim.x) >> 6;
  int chunk = (NN + nw - 1) / nw;
  int lo = wid * chunk;
  int hi = lo + chunk; if (hi > NN) hi = NN;
  if (lo >= hi) return;
  int g = batch[lo];
  float acc = 0.f, cnt = 0.f;
  for (int i = lo; i < hi; ++i) {
    int gi = batch[i];
    if (gi != g) {
      atomicAdd(&pooled[g * CCH + c], acc);
      if (c == 0) atomicAdd(&counts[g], cnt);
      g = gi; acc = 0.f; cnt = 0.f;
    }
    acc += h[(size_t)i * CCH + c];
    cnt += 1.f;
  }
  atomicAdd(&pooled[g * CCH + c], acc);
  if (c == 0) atomicAdd(&counts[g], cnt);
}

__global__ __launch_bounds__(128) void mlp_kernel(const float* __restrict__ pooled,
    const float* __restrict__ counts, const float* __restrict__ hid_w,
    const float* __restrict__ hid_b, const float* __restrict__ out_w,
    const float* __restrict__ out_b, float* __restrict__ out) {
  int g = blockIdx.x;
  int t = threadIdx.x;  // 128 threads
  __shared__ float p[64], hid[128];
  if (t < 64) {
    float cnt = counts[g];
    cnt = cnt > 1.f ? cnt : 1.f;
    p[t] = pooled[g * CCH + t] / cnt;
  }
  __syncthreads();
  float acc = hid_b[t];
  for (int k = 0; k < 64; ++k) acc = fmaf(p[k], hid_w[k * HID + t], acc);
  acc = acc > 0.f ? acc : 0.f;
  hid[t] = acc;
  __syncthreads();
  if (t < 64) {
    float o = out_b[t];
    for (int j = 0; j < 128; ++j) o = fmaf(hid[j], out_w[j * CCH + t], o);
    out[g * CCH + t] = o;
  }
}

extern "C" void kernel_launch(void* const* d_in, const int* in_sizes, int n_in,
                              void* d_out, int out_size, void* d_ws, size_t ws_size,
                              hipStream_t stream) {
  const int* x       = (const int*)d_in[0];
  const int* ei      = (const int*)d_in[1];
  const int* batch   = (const int*)d_in[2];
  const float* emb   = (const float*)d_in[3];
  const float* gamma = (const float*)d_in[4];
  const float* beta  = (const float*)d_in[5];
  const float* convw = (const float*)d_in[6];
  const float* convb = (const float*)d_in[7];
  const float* hid_w = (const float*)d_in[8];
  const float* hid_b = (const float*)d_in[9];
  const float* out_w = (const float*)d_in[10];
  const float* out_b = (const float*)d_in[11];
  float* out = (float*)d_out;

  float* ws     = (float*)d_ws;
  float* stats  = ws + OFF_STATS;
  float* pooled = ws + OFF_POOLED;
  float* counts = ws + OFF_COUNTS;
  int*   gcur   = (int*)(ws + OFF_GCUR);
  int*   deg    = (int*)(ws + OFF_DEG);
  float* dis    = ws + OFF_DIS;
  int*   offs   = (int*)(ws + OFF_OFFS);
  int*   part   = (int*)(ws + OFF_PART);
  int*   csrsrc = (int*)(ws + OFF_CSRSRC);
  float* h      = ws + OFF_H;
  unsigned short* hwb = (unsigned short*)(ws + OFF_HW);
  unsigned int* staging = (unsigned int*)(ws + OFF_HW);  // aliases hwb (used before gemm)

  hipMemsetAsync(ws, 0, MEMSET_F * sizeof(float), stream);
  init_deg_kernel<<<(NN + 255) / 256, 256, 0, stream>>>(deg);
  count_deg_kernel<<<(NE + 255) / 256, 256, 0, stream>>>(ei, deg);
  scan_blocks_kernel<<<SCAN_NB, 256, 0, stream>>>(deg, offs, part, dis);
  scan_carry_kernel<<<1, 256, 0, stream>>>(part);
  scan_apply_kernel<<<SCAN_NB, 256, 0, stream>>>(part, offs);
  bucket_scatter_kernel<<<(NE + EDGE_CHUNK - 1) / EDGE_CHUNK, 256, 0, stream>>>(ei, offs, gcur, staging);
  bucket_fill_kernel<<<SCAN_NB, 256, 0, stream>>>(staging, offs, csrsrc);
  embed_stats_kernel<<<512, 256, 0, stream>>>(x, emb, h, stats);

  for (int l = 0; l < NLAYER; ++l) {
    gemm_kernel<<<(NN + 127) / 128, 256, 0, stream>>>(h, convw + l * 4096,
                                                      gamma + l * 64, beta + l * 64,
                                                      stats + l * 128, dis, hwb);
    aggregate_kernel<<<2048, 256, 0, stream>>>(h, hwb, dis, offs, csrsrc,
                                               convb + l * 64, stats + (l + 1) * 128);
  }

  pool_kernel<<<128, 256, 0, stream>>>(h, batch, pooled, counts);
  mlp_kernel<<<NG, 128, 0, stream>>>(pooled, counts, hid_w, hid_b, out_w, out_b, out);
}

// Round 10
// 840.411 us; speedup vs baseline: 4.2018x; 1.0168x over previous
//
#include <hip/hip_runtime.h>

#define NN 50000
#define NE 1200000
#define CCH 64
#define NLAYER 8
#define HID 128
#define NG 128
#define BN_EPS 1e-5f
#define SCAN_NB ((NN + 255) / 256)   // 196 blocks / buckets
#define EDGE_CHUNK 8192              // edges per bucket_scatter block

// ---- workspace layout (offsets in floats) ----
// [stats | pooled | counts | gcur | deg] <- zeroed by one memsetAsync
enum : size_t {
  OFF_STATS  = 0,
  OFF_POOLED = 1152,
  OFF_COUNTS = 9344,
  OFF_GCUR   = 9472,       // 196 bucket cursors (ints)
  OFF_DEG    = 9728,       // int[N] (zeroed; counts real in-edges only)
  MEMSET_F   = 59728,
  OFF_DIS    = 59728,
  OFF_OFFS   = 109728,     // N+1 (+pad)
  OFF_PART   = 159732,     // 256 block partials
  OFF_CSRSRC = 159988,     // ushort[E] (src < 65536)
  OFF_H      = 759988,     // float[N*64]
  OFF_HW     = 3959988,    // ushort[4][N][16] (bf16 channel slabs); staging aliases
  WS_FLOATS  = 5559988
};

__device__ __forceinline__ float bf2f(unsigned int hs) {
  union { unsigned int u; float f; } c; c.u = hs << 16; return c.f;
}
__device__ __forceinline__ unsigned int f2bf(float x) {
  union { float f; unsigned int u; } c; c.f = x;
  return (c.u + 0x7fffu + ((c.u >> 16) & 1u)) >> 16;  // RNE
}

__global__ void count_deg_kernel(const int* __restrict__ ei, int* __restrict__ deg) {
  int e = blockIdx.x * blockDim.x + threadIdx.x;
  if (e < NE) atomicAdd(&deg[ei[NE + e]], 1);
}

// Per-block exclusive scan of deg (real edges); dis = rsqrt(deg+1) (self-loop).
__global__ __launch_bounds__(256) void scan_blocks_kernel(const int* __restrict__ deg,
    int* __restrict__ offs, int* __restrict__ partials, float* __restrict__ dis) {
  int i = blockIdx.x * 256 + threadIdx.x;
  int v = 0;
  if (i < NN) {
    int d = deg[i];
    v = d;
    dis[i] = rsqrtf((float)(d + 1));
  }
  __shared__ int sm[256];
  sm[threadIdx.x] = v;
  __syncthreads();
  for (int d = 1; d < 256; d <<= 1) {
    int add = (threadIdx.x >= d) ? sm[threadIdx.x - d] : 0;
    __syncthreads();
    sm[threadIdx.x] += add;
    __syncthreads();
  }
  if (i < NN) offs[i] = sm[threadIdx.x] - v;  // exclusive within block
  if (threadIdx.x == 255) partials[blockIdx.x] = sm[255];
}

__global__ __launch_bounds__(256) void scan_carry_kernel(int* __restrict__ partials) {
  int t = threadIdx.x;
  int v = (t < SCAN_NB) ? partials[t] : 0;
  __shared__ int sm[256];
  sm[t] = v;
  __syncthreads();
  for (int d = 1; d < 256; d <<= 1) {
    int add = (t >= d) ? sm[t - d] : 0;
    __syncthreads();
    sm[t] += add;
    __syncthreads();
  }
  if (t < SCAN_NB) partials[t] = sm[t] - v;  // exclusive carry per block
}

__global__ __launch_bounds__(256) void scan_apply_kernel(const int* __restrict__ partials,
    int* __restrict__ offs) {
  int i = blockIdx.x * 256 + threadIdx.x;
  if (i < NN) offs[i] += partials[blockIdx.x];
  if (i == 0) offs[NN] = NE;
}

// ---- CSR build phase A: bucket edges by dst>>8 into staging (packed u32).
__global__ __launch_bounds__(256) void bucket_scatter_kernel(const int* __restrict__ ei,
    const int* __restrict__ offs, int* __restrict__ gcur, unsigned int* __restrict__ staging) {
  __shared__ int bcnt[SCAN_NB];
  __shared__ int bbase[SCAN_NB];
  int tid = threadIdx.x;
  int lo = blockIdx.x * EDGE_CHUNK;
  int hi = lo + EDGE_CHUNK; if (hi > NE) hi = NE;
  for (int b = tid; b < SCAN_NB; b += 256) bcnt[b] = 0;
  __syncthreads();
  for (int e = lo + tid; e < hi; e += 256)
    atomicAdd(&bcnt[ei[NE + e] >> 8], 1);
  __syncthreads();
  for (int b = tid; b < SCAN_NB; b += 256) {
    int c = bcnt[b];
    bbase[b] = c ? (offs[b << 8] + atomicAdd(&gcur[b], c)) : 0;
    bcnt[b] = 0;
  }
  __syncthreads();
  for (int e = lo + tid; e < hi; e += 256) {
    int src = ei[e], dst = ei[NE + e];
    int b = dst >> 8;
    int p = bbase[b] + atomicAdd(&bcnt[b], 1);
    staging[p] = ((unsigned int)(dst & 255) << 16) | (unsigned int)src;
  }
}

// ---- CSR build phase B: one block per bucket; LDS cursors; ushort placement.
__global__ __launch_bounds__(256) void bucket_fill_kernel(const unsigned int* __restrict__ staging,
    const int* __restrict__ offs, unsigned short* __restrict__ csr_src) {
  __shared__ int ncur[256];
  int b = blockIdx.x;
  int nodeBase = b << 8;
  int tid = threadIdx.x;
  int nHi = nodeBase + 256; if (nHi > NN) nHi = NN;
  int nLoc = nHi - nodeBase;
  if (tid < nLoc) ncur[tid] = offs[nodeBase + tid];
  __syncthreads();
  int r0 = offs[nodeBase], r1 = offs[nHi];
  for (int e = r0 + tid; e < r1; e += 256) {
    unsigned int v = staging[e];
    int p = atomicAdd(&ncur[v >> 16], 1);
    csr_src[p] = (unsigned short)(v & 0xffffu);
  }
}

// h = emb[x]; also accumulate BN stats for layer 0
__global__ __launch_bounds__(256) void embed_stats_kernel(const int* __restrict__ x,
    const float* __restrict__ emb, float* __restrict__ h, float* __restrict__ stats0) {
  int c = threadIdx.x & 63;
  int wave = (blockIdx.x * blockDim.x + threadIdx.x) >> 6;
  int nw = (gridDim.x * blockDim.x) >> 6;
  float ls = 0.f, lq = 0.f;
  for (int i = wave; i < NN; i += nw) {
    float v = emb[x[i] * CCH + c];
    h[(size_t)i * CCH + c] = v;
    ls += v; lq += v * v;
  }
  __shared__ float s1[256], s2[256];
  s1[threadIdx.x] = ls; s2[threadIdx.x] = lq;
  __syncthreads();
  if (threadIdx.x < 64) {
    float a = s1[threadIdx.x] + s1[threadIdx.x + 64] + s1[threadIdx.x + 128] + s1[threadIdx.x + 192];
    float b = s2[threadIdx.x] + s2[threadIdx.x + 64] + s2[threadIdx.x + 128] + s2[threadIdx.x + 192];
    atomicAdd(&stats0[c], a);
    atomicAdd(&stats0[64 + c], b);
  }
}

// Fused BN-fold + GEMM: hw' = bf16(((h-m)*rstd*gamma+beta) @ W * dis[node]),
// written in channel-slab layout: hwb[slab][node][16ch], slab = ch/16.
// bias2 computed with 4-way k-split (parallel, no serial 64-loop).
__global__ __launch_bounds__(256) void gemm_kernel(const float* __restrict__ h,
    const float* __restrict__ W, const float* __restrict__ gamma,
    const float* __restrict__ beta, const float* __restrict__ stats,
    const float* __restrict__ dis, unsigned short* __restrict__ hwb) {
  __shared__ float Ws[64 * 64];
  __shared__ float HsT[64 * 133];
  __shared__ float sm_a[64], sm_b2[64], sm_bias2[64];
  __shared__ float sm_part[4][64];
  int tid = threadIdx.x;
  if (tid < 64) {
    float inv_n = 1.0f / (float)NN;
    float m = stats[tid] * inv_n;
    float var = stats[64 + tid] * inv_n - m * m;
    float rstd = rsqrtf(var + BN_EPS);
    float av = gamma[tid] * rstd;
    sm_a[tid] = av;
    sm_b2[tid] = beta[tid] - m * av;
  }
  __syncthreads();
  int nodeBase = blockIdx.x * 128;
  for (int idx = tid; idx < 4096; idx += 256) Ws[idx] = sm_a[idx >> 6] * W[idx];
  for (int idx = tid; idx < 8192; idx += 256) {
    int node = idx >> 6, c = idx & 63;
    int gn = nodeBase + node;
    float v = (gn < NN) ? h[(size_t)gn * CCH + c] : 0.f;
    HsT[c * 133 + node] = v;
  }
  {  // bias2[j] = sum_k b2[k]*W[k][j], k-split over 4 groups of 16
    int j = tid & 63, kg = tid >> 6;
    float s = 0.f;
#pragma unroll
    for (int k = kg * 16; k < kg * 16 + 16; ++k) s += sm_b2[k] * W[k * 64 + j];
    sm_part[kg][j] = s;
  }
  __syncthreads();
  if (tid < 64)
    sm_bias2[tid] = sm_part[0][tid] + sm_part[1][tid] + sm_part[2][tid] + sm_part[3][tid];
  __syncthreads();
  int tc = tid & 15;   // channels tc*4..+3
  int tr = tid >> 4;   // nodes tr*8..+7
  float4 bb = *(const float4*)&sm_bias2[tc * 4];
  float acc[8][4];
#pragma unroll
  for (int i = 0; i < 8; ++i) { acc[i][0] = bb.x; acc[i][1] = bb.y; acc[i][2] = bb.z; acc[i][3] = bb.w; }
#pragma unroll 2
  for (int k = 0; k < 64; ++k) {
    float4 wv = *(const float4*)&Ws[k * 64 + tc * 4];
    float4 h0 = *(const float4*)&HsT[k * 133 + tr * 8];
    float4 h1 = *(const float4*)&HsT[k * 133 + tr * 8 + 4];
    float hv[8] = {h0.x, h0.y, h0.z, h0.w, h1.x, h1.y, h1.z, h1.w};
    float wl[4] = {wv.x, wv.y, wv.z, wv.w};
#pragma unroll
    for (int i = 0; i < 8; ++i)
#pragma unroll
      for (int j = 0; j < 4; ++j) acc[i][j] = fmaf(hv[i], wl[j], acc[i][j]);
  }
  unsigned short* slabp = hwb + (size_t)(tc >> 2) * NN * 16;
  int coff = (tc & 3) * 4;
#pragma unroll
  for (int i = 0; i < 8; ++i) {
    int gn = nodeBase + tr * 8 + i;
    if (gn < NN) {
      float dv = dis[gn];
      uint2 o;
      o.x = f2bf(acc[i][0] * dv) | (f2bf(acc[i][1] * dv) << 16);
      o.y = f2bf(acc[i][2] * dv) | (f2bf(acc[i][3] * dv) << 16);
      *(uint2*)&slabp[(size_t)gn * 16 + coff] = o;
    }
  }
}

// h = relu(h + conv_b + dis_i*(hw'_i + sum_in hw'_src)); fused BN stats.
// 4-way channel-slab split with XCD affinity (slab = blockIdx&3; each XCD's
// 1.6MB slab is L2-resident). csr_src is ushort (halved stream). 32 edges
// in flight per wave (4 octets A/B/C/D).
__global__ __launch_bounds__(256) void aggregate_kernel(float* __restrict__ h,
    const unsigned short* __restrict__ hwb, const float* __restrict__ dis,
    const int* __restrict__ offs, const unsigned short* __restrict__ csr_src,
    const float* __restrict__ conv_b_l, float* __restrict__ stats_next) {
  int tid = threadIdx.x;
  int b = blockIdx.x;
  int slab = b & 3;                          // XCD = b&7; slab = XCD&3
  int subIdx = (b >> 3) * 2 + ((b >> 2) & 1);  // block index among those sharing slab
  int wid = subIdx * 4 + (tid >> 6);
  int nwSlab = (gridDim.x >> 2) * 4;         // waves per slab
  int chunk = (NN + nwSlab - 1) / nwSlab;
  int lo = wid * chunk;
  int hi = lo + chunk; if (hi > NN) hi = NN;
  int lane = tid & 63;
  int slot = lane >> 3;                      // which edge of the octet
  int l = lane & 7;                          // channel pair within slab (16 ch)
  int cbase = slab * 16;
  const unsigned short* slabp = hwb + (size_t)slab * NN * 16;
  float2 cb = ((const float2*)conv_b_l)[slab * 8 + l];
  float ls0 = 0.f, ls1 = 0.f, lq0 = 0.f, lq1 = 0.f;
  for (int i = lo; i < hi; ++i) {
    float a0 = 0.f, a1 = 0.f;
    if (slot == 0) {  // self term (pre-scaled by dis_i)
      unsigned int sv = *(const unsigned int*)&slabp[(size_t)i * 16 + 2 * l];
      a0 = bf2f(sv & 0xffffu); a1 = bf2f(sv >> 16);
    }
    int e0 = offs[i], e1 = offs[i + 1];
    for (int base = e0; base < e1; base += 32) {
      int iA = base + slot, iB = iA + 8, iC = iA + 16, iD = iA + 24;
      int okA = iA < e1, okB = iB < e1, okC = iC < e1, okD = iD < e1;
      int sA = csr_src[okA ? iA : e1 - 1];
      int sB = csr_src[okB ? iB : e1 - 1];
      int sC = csr_src[okC ? iC : e1 - 1];
      int sD = csr_src[okD ? iD : e1 - 1];
      unsigned int uA = *(const unsigned int*)&slabp[(size_t)sA * 16 + 2 * l];
      unsigned int uB = *(const unsigned int*)&slabp[(size_t)sB * 16 + 2 * l];
      unsigned int uC = *(const unsigned int*)&slabp[(size_t)sC * 16 + 2 * l];
      unsigned int uD = *(const unsigned int*)&slabp[(size_t)sD * 16 + 2 * l];
      uA = okA ? uA : 0u;
      uB = okB ? uB : 0u;
      uC = okC ? uC : 0u;
      uD = okD ? uD : 0u;
      a0 += bf2f(uA & 0xffffu) + bf2f(uB & 0xffffu) + bf2f(uC & 0xffffu) + bf2f(uD & 0xffffu);
      a1 += bf2f(uA >> 16) + bf2f(uB >> 16) + bf2f(uC >> 16) + bf2f(uD >> 16);
    }
    a0 += __shfl_xor(a0, 8); a0 += __shfl_xor(a0, 16); a0 += __shfl_xor(a0, 32);
    a1 += __shfl_xor(a1, 8); a1 += __shfl_xor(a1, 16); a1 += __shfl_xor(a1, 32);
    if (slot == 0) {
      float2 hv = ((const float2*)h)[(size_t)i * 32 + slab * 8 + l];
      float d = dis[i];
      float v0 = hv.x + cb.x + d * a0;
      float v1 = hv.y + cb.y + d * a1;
      v0 = v0 > 0.f ? v0 : 0.f;
      v1 = v1 > 0.f ? v1 : 0.f;
      float2 o; o.x = v0; o.y = v1;
      ((float2*)h)[(size_t)i * 32 + slab * 8 + l] = o;
      ls0 += v0; lq0 += v0 * v0; ls1 += v1; lq1 += v1 * v1;
    }
  }
  __shared__ float2 s1[256], s2[256];
  float2 t1; t1.x = ls0; t1.y = ls1;
  float2 t2; t2.x = lq0; t2.y = lq1;
  s1[tid] = t1; s2[tid] = t2;
  __syncthreads();
  if (tid < 16) {  // this block covers 16 channels: cbase + tid
    int pair = tid >> 1, comp = tid & 1;   // slot-0 lanes 0..7 of each wave
    float a = 0.f, bb = 0.f;
#pragma unroll
    for (int w = 0; w < 4; ++w) {
      float2 u1 = s1[w * 64 + pair];
      float2 u2 = s2[w * 64 + pair];
      a += comp ? u1.y : u1.x;
      bb += comp ? u2.y : u2.x;
    }
    atomicAdd(&stats_next[cbase + tid], a);
    atomicAdd(&stats_next[64 + cbase + tid], bb);
  }
}

// batch is SORTED: chunked per-wave register accumulation, one atomic per
// graph-boundary per channel.
__global__ __launch_bounds__(256) void pool_kernel(const float* __restrict__ h,
    const int* __restrict__ batch, float* __restrict__ pooled, float* __restrict__ counts) {
  int c = threadIdx.x & 63;
  int wid = (blockIdx.x * blockDim.x + threadIdx.x) >> 6;
  int nw = (gridDim.x * blockDim.x) >> 6;
  int chunk = (NN + nw - 1) / nw;
  int lo = wid * chunk;
  int hi = lo + chunk; if (hi > NN) hi = NN;
  if (lo >= hi) return;
  int g = batch[lo];
  float acc = 0.f, cnt = 0.f;
  for (int i = lo; i < hi; ++i) {
    int gi = batch[i];
    if (gi != g) {
      atomicAdd(&pooled[g * CCH + c], acc);
      if (c == 0) atomicAdd(&counts[g], cnt);
      g = gi; acc = 0.f; cnt = 0.f;
    }
    acc += h[(size_t)i * CCH + c];
    cnt += 1.f;
  }
  atomicAdd(&pooled[g * CCH + c], acc);
  if (c == 0) atomicAdd(&counts[g], cnt);
}

__global__ __launch_bounds__(128) void mlp_kernel(const float* __restrict__ pooled,
    const float* __restrict__ counts, const float* __restrict__ hid_w,
    const float* __restrict__ hid_b, const float* __restrict__ out_w,
    const float* __restrict__ out_b, float* __restrict__ out) {
  int g = blockIdx.x;
  int t = threadIdx.x;  // 128 threads
  __shared__ float p[64], hid[128];
  if (t < 64) {
    float cnt = counts[g];
    cnt = cnt > 1.f ? cnt : 1.f;
    p[t] = pooled[g * CCH + t] / cnt;
  }
  __syncthreads();
  float acc = hid_b[t];
  for (int k = 0; k < 64; ++k) acc = fmaf(p[k], hid_w[k * HID + t], acc);
  acc = acc > 0.f ? acc : 0.f;
  hid[t] = acc;
  __syncthreads();
  if (t < 64) {
    float o = out_b[t];
    for (int j = 0; j < 128; ++j) o = fmaf(hid[j], out_w[j * CCH + t], o);
    out[g * CCH + t] = o;
  }
}

extern "C" void kernel_launch(void* const* d_in, const int* in_sizes, int n_in,
                              void* d_out, int out_size, void* d_ws, size_t ws_size,
                              hipStream_t stream) {
  const int* x       = (const int*)d_in[0];
  const int* ei      = (const int*)d_in[1];
  const int* batch   = (const int*)d_in[2];
  const float* emb   = (const float*)d_in[3];
  const float* gamma = (const float*)d_in[4];
  const float* beta  = (const float*)d_in[5];
  const float* convw = (const float*)d_in[6];
  const float* convb = (const float*)d_in[7];
  const float* hid_w = (const float*)d_in[8];
  const float* hid_b = (const float*)d_in[9];
  const float* out_w = (const float*)d_in[10];
  const float* out_b = (const float*)d_in[11];
  float* out = (float*)d_out;

  float* ws     = (float*)d_ws;
  float* stats  = ws + OFF_STATS;
  float* pooled = ws + OFF_POOLED;
  float* counts = ws + OFF_COUNTS;
  int*   gcur   = (int*)(ws + OFF_GCUR);
  int*   deg    = (int*)(ws + OFF_DEG);
  float* dis    = ws + OFF_DIS;
  int*   offs   = (int*)(ws + OFF_OFFS);
  int*   part   = (int*)(ws + OFF_PART);
  unsigned short* csrsrc = (unsigned short*)(ws + OFF_CSRSRC);
  float* h      = ws + OFF_H;
  unsigned short* hwb = (unsigned short*)(ws + OFF_HW);
  unsigned int* staging = (unsigned int*)(ws + OFF_HW);  // aliases hwb (used before gemm)

  hipMemsetAsync(ws, 0, MEMSET_F * sizeof(float), stream);
  count_deg_kernel<<<(NE + 255) / 256, 256, 0, stream>>>(ei, deg);
  scan_blocks_kernel<<<SCAN_NB, 256, 0, stream>>>(deg, offs, part, dis);
  scan_carry_kernel<<<1, 256, 0, stream>>>(part);
  scan_apply_kernel<<<SCAN_NB, 256, 0, stream>>>(part, offs);
  bucket_scatter_kernel<<<(NE + EDGE_CHUNK - 1) / EDGE_CHUNK, 256, 0, stream>>>(ei, offs, gcur, staging);
  bucket_fill_kernel<<<SCAN_NB, 256, 0, stream>>>(staging, offs, csrsrc);
  embed_stats_kernel<<<512, 256, 0, stream>>>(x, emb, h, stats);

  for (int l = 0; l < NLAYER; ++l) {
    gemm_kernel<<<(NN + 127) / 128, 256, 0, stream>>>(h, convw + l * 4096,
                                                      gamma + l * 64, beta + l * 64,
                                                      stats + l * 128, dis, hwb);
    aggregate_kernel<<<2048, 256, 0, stream>>>(h, hwb, dis, offs, csrsrc,
                                               convb + l * 64, stats + (l + 1) * 128);
  }

  pool_kernel<<<128, 256, 0, stream>>>(h, batch, pooled, counts);
  mlp_kernel<<<NG, 128, 0, stream>>>(pooled, counts, hid_w, hid_b, out_w, out_b, out);
}